// Round 2
// baseline (690.768 us; speedup 1.0000x reference)
//
#include <hip/hip_runtime.h>
#include <math.h>

#define EMBED 1024
#define HEADS 16
#define HD    64
#define SEQ   2048
#define BATCH 4
#define ROWS  (BATCH * SEQ)   // 8192

typedef _Float16 f16;
typedef __attribute__((ext_vector_type(8))) _Float16 f16x8;
typedef __attribute__((ext_vector_type(4))) _Float16 f16x4;
typedef __attribute__((ext_vector_type(2))) _Float16 f16x2;
typedef __attribute__((ext_vector_type(4))) float    fx4;

typedef __attribute__((address_space(3))) char  lds_char;
typedef __attribute__((address_space(1))) const char glb_char;

#define SCALE_Q 0.18033688011112042f   // 0.125 * log2(e), folded into Q at GEMM1

// ---------------------------------------------------------------------------
// Fused prep: one dispatch does all three input conversions.
//   blocks [0, 8192)        : x fp32 -> f16 (4 elems/thread)
//   blocks [8192, 11264)    : Wqkv [1024][3072] -> Wqt [3072][1024] f16
//   blocks [11264, 12288)   : Wproj [1024][1024] -> Wpt [1024][1024] f16
// ---------------------------------------------------------------------------
__global__ __launch_bounds__(256) void prep(const float* __restrict__ x,
                                            f16* __restrict__ x_h,
                                            const float* __restrict__ Wqkv,
                                            f16* __restrict__ Wqt,
                                            const float* __restrict__ Wproj,
                                            f16* __restrict__ Wpt) {
    const int blk = blockIdx.x;
    if (blk < 8192) {
        const int i = (blk * 256 + threadIdx.x) * 4;
        const float4 v = *(const float4*)(x + i);
        f16x4 o = {(f16)v.x, (f16)v.y, (f16)v.z, (f16)v.w};
        *(f16x4*)(x_h + i) = o;
        return;
    }
    __shared__ float t[32][33];
    const float* W;
    f16* Wt;
    int N, bx, by;
    if (blk < 8192 + 3072) {
        const int b2 = blk - 8192;
        W = Wqkv; Wt = Wqt; N = 3072; bx = b2 % 96; by = b2 / 96;
    } else {
        const int b2 = blk - 8192 - 3072;
        W = Wproj; Wt = Wpt; N = 1024; bx = b2 % 32; by = b2 / 32;
    }
    const int tx = threadIdx.x & 31, ty = threadIdx.x >> 5;   // 32 x 8
    const int k0 = by * 32, n0 = bx * 32;
    #pragma unroll
    for (int i = 0; i < 4; i++)
        t[ty + i * 8][tx] = W[(size_t)(k0 + ty + i * 8) * N + n0 + tx];
    __syncthreads();
    #pragma unroll
    for (int i = 0; i < 4; i++)
        Wt[(size_t)(n0 + ty + i * 8) * 1024 + k0 + tx] = (f16)t[tx][ty + i * 8];
}

// ---------------------------------------------------------------------------
// f16 MFMA GEMM (m97 structure): 128x128 tile, 256 threads, BK=32.
// MODE 0: C = A@Bt^T + bias, fp32 out (proj GEMM).
// MODE 1: qkv GEMM; epilogue splits by n-region (uniform per block):
//   n<1024  -> Q, scaled by SCALE_Q, layout qH[b][s][h*64+d]
//   n<2048  -> K, layout kH[b][h][s][d]
//   else    -> V, layout vT[b][h][d][perm(s)], perm(s)=(s&~31)|((s&15)<<1)|((s>>4)&1)
// ---------------------------------------------------------------------------
template <int MODE>
__global__ __launch_bounds__(256) void gemm_f16k(const f16* __restrict__ A,
                                                 const f16* __restrict__ Bt,
                                                 const float* __restrict__ bias,
                                                 float* __restrict__ Cf,
                                                 f16* __restrict__ qH,
                                                 f16* __restrict__ kH,
                                                 f16* __restrict__ vT,
                                                 int M, int N, int K) {
    __shared__ alignas(16) f16 As[128][32];
    __shared__ alignas(16) f16 Bs[128][32];
    const int tid  = threadIdx.x;
    const int wave = tid >> 6;
    const int lane = tid & 63;
    const int quad = lane >> 4;
    const int l16  = lane & 15;
    const int m0   = blockIdx.y * 128;
    const int n0   = blockIdx.x * 128;
    const int wm   = wave & 1;
    const int wn   = wave >> 1;

    fx4 acc[4][4];
    #pragma unroll
    for (int i = 0; i < 4; i++)
        #pragma unroll
        for (int j = 0; j < 4; j++)
            acc[i][j] = (fx4){0.f, 0.f, 0.f, 0.f};

    lds_char* asb = (lds_char*)&As[0][0];
    lds_char* bsb = (lds_char*)&Bs[0][0];

    for (int k0 = 0; k0 < K; k0 += 32) {
        __syncthreads();
        #pragma unroll
        for (int r = 0; r < 2; r++) {
            const int g   = r * 4 + wave;
            const int c   = g * 64 + lane;
            const int row = c >> 2;
            const int ko  = (c & 3) * 8;
            __builtin_amdgcn_global_load_lds(
                (glb_char*)(A + (size_t)(m0 + row) * K + k0 + ko),
                asb + g * 1024, 16, 0, 0);
            __builtin_amdgcn_global_load_lds(
                (glb_char*)(Bt + (size_t)(n0 + row) * K + k0 + ko),
                bsb + g * 1024, 16, 0, 0);
        }
        __syncthreads();

        f16x8 af[4], bf[4];
        #pragma unroll
        for (int t = 0; t < 4; t++) {
            af[t] = *(const f16x8*)&As[wm * 64 + t * 16 + l16][quad * 8];
            bf[t] = *(const f16x8*)&Bs[wn * 64 + t * 16 + l16][quad * 8];
        }
        #pragma unroll
        for (int i = 0; i < 4; i++)
            #pragma unroll
            for (int j = 0; j < 4; j++)
                acc[i][j] = __builtin_amdgcn_mfma_f32_16x16x32_f16(af[i], bf[j], acc[i][j], 0, 0, 0);
    }

    const int region = n0 >> 10;
    #pragma unroll
    for (int i = 0; i < 4; i++) {
        const int mb = m0 + wm * 64 + i * 16 + quad * 4;
        #pragma unroll
        for (int j = 0; j < 4; j++) {
            const int n  = n0 + wn * 64 + j * 16 + l16;
            const float bn = bias[n];
            #pragma unroll
            for (int r = 0; r < 4; r++) {
                const int m = mb + r;
                const float v = acc[i][j][r] + bn;
                if (MODE == 0) {
                    Cf[(size_t)m * N + n] = v;
                } else {
                    const int b = m >> 11, s = m & 2047;
                    if (region == 0) {
                        qH[(size_t)m * EMBED + n] = (f16)(v * SCALE_Q);
                    } else if (region == 1) {
                        const int np = n - 1024, hh = np >> 6, d = np & 63;
                        kH[(((size_t)(b * 16 + hh) * SEQ + s) << 6) + d] = (f16)v;
                    } else {
                        const int np = n - 2048, hh = np >> 6, d = np & 63;
                        const int sp = (s & ~31) | ((s & 15) << 1) | ((s >> 4) & 1);
                        vT[((size_t)(b * 16 + hh) * HD + d) * SEQ + sp] = (f16)v;
                    }
                }
            }
        }
    }
}

// ---------------------------------------------------------------------------
// MFMA flash attention v6: double-buffered K/V (T3 minimum 2-phase).
// Block = 256 threads = 4 waves; wave = 32 queries (2 qsets); key tile = 64.
// Loop: STAGE(kb+1, buf^1) issued BEFORE fragment reads / compute of tile kb;
// single __syncthreads() per iter (its vmcnt(0) drain lands after ~400cy of
// MFMA+exp compute, so the staging latency is hidden). One barrier/iter.
// LDS = 40.0 KB exactly -> 4 blocks/CU (matches grid limit: 1024 blk/256 CU).
// P buffer: PS=64 with 16B-chunk XOR swizzle (chunk ^= row&7) applied on BOTH
// store and read -> store 2-way (free), b128 read bank-balanced.
// Softmax: p = 2^score (no max/shift; cancels in normalization).
// Row sums via PV MFMA against all-ones B fragment (C-layout, no shuffles).
// s_setprio(1) around MFMA clusters (attn-measured +4-7%).
// XCD swizzle: 16 query-blocks of one (b,h) share one XCD's L2.
// ---------------------------------------------------------------------------
__global__ __launch_bounds__(256, 4) void attn_mfma(const f16* __restrict__ qH,
                                                    const f16* __restrict__ kH,
                                                    const f16* __restrict__ vT,
                                                    f16* __restrict__ ctx) {
    __shared__ alignas(16) f16 Ks[2][64 * 64];   // 16 KB dbuf, swizzled [key][dim]
    __shared__ alignas(16) f16 Vt[2][64 * 64];   // 16 KB dbuf, swizzled [dim][keycol]
    __shared__ alignas(16) f16 Pl[4][16 * 64];   // 8 KB, chunk-xor swizzled

    const int tid  = threadIdx.x;
    const int wave = tid >> 6;
    const int lane = tid & 63;
    const int quad = lane >> 4;
    const int l16  = lane & 15;

    // XCD-aware bijective swizzle: grid 1024 % 8 == 0.
    const int bid = (int)blockIdx.x;
    const int swz = (bid & 7) * 128 + (bid >> 3);
    const int qb = swz & 15;
    const int bh = swz >> 4;
    const int h  = bh & 15;
    const int b  = bh >> 4;
    const int q0 = qb * 128 + wave * 32;

    const f16* kB = kH + (size_t)bh * SEQ * HD;
    const f16* vB = vT + (size_t)bh * HD * SEQ;

    // Q fragments (pre-scaled by GEMM1)
    f16x8 qf[2][2];
    #pragma unroll
    for (int s = 0; s < 2; s++) {
        const f16* qp = qH + (size_t)(b * SEQ + q0 + s * 16 + l16) * EMBED + h * HD;
        #pragma unroll
        for (int c = 0; c < 2; c++)
            qf[s][c] = *(const f16x8*)(qp + c * 32 + quad * 8);
    }

    fx4 o[2][4];
    fx4 ls[2];
    #pragma unroll
    for (int s = 0; s < 2; s++) {
        ls[s] = (fx4){0.f, 0.f, 0.f, 0.f};
        #pragma unroll
        for (int dc = 0; dc < 4; dc++)
            o[s][dc] = (fx4){0.f, 0.f, 0.f, 0.f};
    }

    f16x8 ones8;
    #pragma unroll
    for (int j = 0; j < 8; j++) ones8[j] = (f16)1.0f;

    lds_char* ksb = (lds_char*)&Ks[0][0];
    lds_char* vsb = (lds_char*)&Vt[0][0];

    // Stage one 64-key K and V tile into buffer `buf` (8 KB each).
    // Dest is wave-uniform base + lane*16 (global_load_lds contract); the
    // xor swizzle lives in the per-lane GLOBAL source address.
    auto STAGE = [&](int kb, int buf) {
        #pragma unroll
        for (int it = 0; it < 2; it++) {
            const int g  = wave * 2 + it;          // groups 0..7
            const int c  = g * 64 + lane;
            const int r  = c >> 3;
            const int jl = (c & 7) ^ (r & 7);
            __builtin_amdgcn_global_load_lds(
                (glb_char*)(kB + (size_t)(kb * 64 + r) * HD + jl * 8),
                ksb + buf * 8192 + g * 1024, 16, 0, 0);
            __builtin_amdgcn_global_load_lds(
                (glb_char*)(vB + (size_t)r * SEQ + kb * 64 + jl * 8),
                vsb + buf * 8192 + g * 1024, 16, 0, 0);
        }
    };

    STAGE(0, 0);
    __syncthreads();   // vmcnt(0) drain + barrier: tile 0 ready

    for (int kb = 0; kb < SEQ / 64; kb++) {
        const int cur = kb & 1;
        if (kb + 1 < SEQ / 64) STAGE(kb + 1, cur ^ 1);   // issue early; wait at iter end

        const f16* KsC = &Ks[cur][0];
        const f16* VtC = &Vt[cur][0];

        // ---- fragments (swizzled reads, conflict-free) ----
        f16x8 kf[4][2], vf[4][2];
        #pragma unroll
        for (int t = 0; t < 4; t++)
            #pragma unroll
            for (int c2 = 0; c2 < 2; c2++) {
                const int row = l16 + 16 * t;
                kf[t][c2] = *(const f16x8*)&KsC[(row * 8 + ((4 * c2 + quad) ^ (row & 7))) * 8];
            }
        #pragma unroll
        for (int dc = 0; dc < 4; dc++)
            #pragma unroll
            for (int kc = 0; kc < 2; kc++) {
                const int row = 16 * dc + l16;
                vf[dc][kc] = *(const f16x8*)&VtC[(row * 8 + ((4 * kc + quad) ^ (row & 7))) * 8];
            }

        #pragma unroll
        for (int s = 0; s < 2; s++) {
            // QK^T: 4 n-tiles of 16 keys
            fx4 st[4];
            __builtin_amdgcn_s_setprio(1);
            #pragma unroll
            for (int t = 0; t < 4; t++) {
                fx4 z = {0.f, 0.f, 0.f, 0.f};
                st[t] = __builtin_amdgcn_mfma_f32_16x16x32_f16(qf[s][0], kf[t][0], z, 0, 0, 0);
                st[t] = __builtin_amdgcn_mfma_f32_16x16x32_f16(qf[s][1], kf[t][1], st[t], 0, 0, 0);
            }
            __builtin_amdgcn_s_setprio(0);
            // exp2 + packed P store (chunk-xor swizzled, PS=64)
            #pragma unroll
            for (int g = 0; g < 2; g++)
                #pragma unroll
                for (int r = 0; r < 4; r++) {
                    const float pa = exp2f(st[2 * g][r]);
                    const float pb = exp2f(st[2 * g + 1][r]);
                    const f16x2 pk = __builtin_bit_cast(f16x2, __builtin_amdgcn_cvt_pkrtz(pa, pb));
                    const int row = quad * 4 + r;
                    const int cc  = (g * 4 + (l16 >> 2)) ^ (row & 7);
                    *(f16x2*)&Pl[wave][row * 64 + cc * 8 + (l16 & 3) * 2] = pk;
                }
            // PV + ones-column row-sum (same-wave LDS dep, DS in-order, no barrier)
            const f16x8 pf0 = *(const f16x8*)&Pl[wave][l16 * 64 + ((0 + quad) ^ (l16 & 7)) * 8];
            const f16x8 pf1 = *(const f16x8*)&Pl[wave][l16 * 64 + ((4 + quad) ^ (l16 & 7)) * 8];
            __builtin_amdgcn_s_setprio(1);
            #pragma unroll
            for (int dc = 0; dc < 4; dc++) {
                o[s][dc] = __builtin_amdgcn_mfma_f32_16x16x32_f16(pf0, vf[dc][0], o[s][dc], 0, 0, 0);
                o[s][dc] = __builtin_amdgcn_mfma_f32_16x16x32_f16(pf1, vf[dc][1], o[s][dc], 0, 0, 0);
            }
            ls[s] = __builtin_amdgcn_mfma_f32_16x16x32_f16(pf0, ones8, ls[s], 0, 0, 0);
            ls[s] = __builtin_amdgcn_mfma_f32_16x16x32_f16(pf1, ones8, ls[s], 0, 0, 0);
            __builtin_amdgcn_s_setprio(0);
        }

        // Single barrier per iter: drains vmcnt (tile kb+1 staged) and ensures
        // all waves are done reading buf[cur] before iter kb+1 re-stages it.
        __syncthreads();
    }

    // ---- normalize + store (row sums already in C-layout) ----
    #pragma unroll
    for (int s = 0; s < 2; s++) {
        #pragma unroll
        for (int r = 0; r < 4; r++) {
            const float inv = 1.0f / ls[s][r];
            const int q = q0 + s * 16 + quad * 4 + r;
            f16* dst = ctx + (size_t)(b * SEQ + q) * EMBED + h * HD;
            #pragma unroll
            for (int dc = 0; dc < 4; dc++)
                dst[dc * 16 + l16] = (f16)(o[s][dc][r] * inv);
        }
    }
}

// ---------------------------------------------------------------------------
extern "C" void kernel_launch(void* const* d_in, const int* in_sizes, int n_in,
                              void* d_out, int out_size, void* d_ws, size_t ws_size,
                              hipStream_t stream) {
    const float* x     = (const float*)d_in[0];
    const float* Wqkv  = (const float*)d_in[1];
    const float* bqkv  = (const float*)d_in[2];
    const float* Wproj = (const float*)d_in[3];
    const float* bproj = (const float*)d_in[4];
    float* out = (float*)d_out;

    // Workspace (f16 elements, 16B-aligned segments), total ~92 MB.
    f16* x_h = (f16*)d_ws;                          // 8M
    f16* qHb = x_h + (size_t)ROWS * EMBED;          // 8M
    f16* kHb = qHb + (size_t)ROWS * EMBED;          // 8M
    f16* vTb = kHb + (size_t)ROWS * EMBED;          // 8M
    f16* ctx = vTb + (size_t)ROWS * EMBED;          // 8M
    f16* Wqt = ctx + (size_t)ROWS * EMBED;          // 3M
    f16* Wpt = Wqt + (size_t)3 * EMBED * EMBED;     // 1M

    // 0) fused conversions (x, Wqkv^T, Wproj^T)
    prep<<<dim3(12288), dim3(256), 0, stream>>>(x, x_h, Wqkv, Wqt, Wproj, Wpt);

    // 1) qkv GEMM with layout-splitting epilogue
    gemm_f16k<1><<<dim3(3 * EMBED / 128, ROWS / 128), dim3(256), 0, stream>>>(
        x_h, Wqt, bqkv, nullptr, qHb, kHb, vTb, ROWS, 3 * EMBED, EMBED);

    // 2) flash attention
    attn_mfma<<<dim3(64 * 16), dim3(256), 0, stream>>>(qHb, kHb, vTb, ctx);

    // 3) out = ctx @ Wproj + bias (fp32)
    gemm_f16k<0><<<dim3(EMBED / 128, ROWS / 128), dim3(256), 0, stream>>>(
        ctx, Wpt, bproj, out, nullptr, nullptr, nullptr, ROWS, EMBED, EMBED);
}

// Round 3
// 318.915 us; speedup vs baseline: 2.1660x; 2.1660x over previous
//
#include <hip/hip_runtime.h>
#include <math.h>

#define EMBED 1024
#define HEADS 16
#define HD    64
#define SEQ   2048
#define BATCH 4
#define ROWS  (BATCH * SEQ)   // 8192

typedef _Float16 f16;
typedef __attribute__((ext_vector_type(8))) _Float16 f16x8;
typedef __attribute__((ext_vector_type(4))) _Float16 f16x4;
typedef __attribute__((ext_vector_type(2))) _Float16 f16x2;
typedef __attribute__((ext_vector_type(4))) float    fx4;

typedef __attribute__((address_space(3))) char  lds_char;
typedef __attribute__((address_space(1))) const char glb_char;

#define SCALE_Q 0.18033688011112042f   // 0.125 * log2(e), folded into Q at GEMM1

// ---------------------------------------------------------------------------
// Fused prep: one dispatch does all three input conversions.
//   blocks [0, 8192)        : x fp32 -> f16 (4 elems/thread)
//   blocks [8192, 11264)    : Wqkv [1024][3072] -> Wqt [3072][1024] f16
//   blocks [11264, 12288)   : Wproj [1024][1024] -> Wpt [1024][1024] f16
// ---------------------------------------------------------------------------
__global__ __launch_bounds__(256) void prep(const float* __restrict__ x,
                                            f16* __restrict__ x_h,
                                            const float* __restrict__ Wqkv,
                                            f16* __restrict__ Wqt,
                                            const float* __restrict__ Wproj,
                                            f16* __restrict__ Wpt) {
    const int blk = blockIdx.x;
    if (blk < 8192) {
        const int i = (blk * 256 + threadIdx.x) * 4;
        const float4 v = *(const float4*)(x + i);
        f16x4 o = {(f16)v.x, (f16)v.y, (f16)v.z, (f16)v.w};
        *(f16x4*)(x_h + i) = o;
        return;
    }
    __shared__ float t[32][33];
    const float* W;
    f16* Wt;
    int N, bx, by;
    if (blk < 8192 + 3072) {
        const int b2 = blk - 8192;
        W = Wqkv; Wt = Wqt; N = 3072; bx = b2 % 96; by = b2 / 96;
    } else {
        const int b2 = blk - 8192 - 3072;
        W = Wproj; Wt = Wpt; N = 1024; bx = b2 % 32; by = b2 / 32;
    }
    const int tx = threadIdx.x & 31, ty = threadIdx.x >> 5;   // 32 x 8
    const int k0 = by * 32, n0 = bx * 32;
    #pragma unroll
    for (int i = 0; i < 4; i++)
        t[ty + i * 8][tx] = W[(size_t)(k0 + ty + i * 8) * N + n0 + tx];
    __syncthreads();
    #pragma unroll
    for (int i = 0; i < 4; i++)
        Wt[(size_t)(n0 + ty + i * 8) * 1024 + k0 + tx] = (f16)t[tx][ty + i * 8];
}

// ---------------------------------------------------------------------------
// f16 MFMA GEMM (m97 structure): 128x128 tile, 256 threads, BK=32.
// MODE 0: C = A@Bt^T + bias, fp32 out (proj GEMM).
// MODE 1: qkv GEMM; epilogue splits by n-region (uniform per block):
//   n<1024  -> Q, scaled by SCALE_Q, layout qH[b][s][h*64+d]
//   n<2048  -> K, layout kH[b][h][s][d]
//   else    -> V, layout vT[b][h][d][perm(s)], perm(s)=(s&~31)|((s&15)<<1)|((s>>4)&1)
// ---------------------------------------------------------------------------
template <int MODE>
__global__ __launch_bounds__(256) void gemm_f16k(const f16* __restrict__ A,
                                                 const f16* __restrict__ Bt,
                                                 const float* __restrict__ bias,
                                                 float* __restrict__ Cf,
                                                 f16* __restrict__ qH,
                                                 f16* __restrict__ kH,
                                                 f16* __restrict__ vT,
                                                 int M, int N, int K) {
    __shared__ alignas(16) f16 As[128][32];
    __shared__ alignas(16) f16 Bs[128][32];
    const int tid  = threadIdx.x;
    const int wave = tid >> 6;
    const int lane = tid & 63;
    const int quad = lane >> 4;
    const int l16  = lane & 15;
    const int m0   = blockIdx.y * 128;
    const int n0   = blockIdx.x * 128;
    const int wm   = wave & 1;
    const int wn   = wave >> 1;

    fx4 acc[4][4];
    #pragma unroll
    for (int i = 0; i < 4; i++)
        #pragma unroll
        for (int j = 0; j < 4; j++)
            acc[i][j] = (fx4){0.f, 0.f, 0.f, 0.f};

    lds_char* asb = (lds_char*)&As[0][0];
    lds_char* bsb = (lds_char*)&Bs[0][0];

    for (int k0 = 0; k0 < K; k0 += 32) {
        __syncthreads();
        #pragma unroll
        for (int r = 0; r < 2; r++) {
            const int g   = r * 4 + wave;
            const int c   = g * 64 + lane;
            const int row = c >> 2;
            const int ko  = (c & 3) * 8;
            __builtin_amdgcn_global_load_lds(
                (glb_char*)(A + (size_t)(m0 + row) * K + k0 + ko),
                asb + g * 1024, 16, 0, 0);
            __builtin_amdgcn_global_load_lds(
                (glb_char*)(Bt + (size_t)(n0 + row) * K + k0 + ko),
                bsb + g * 1024, 16, 0, 0);
        }
        __syncthreads();

        f16x8 af[4], bf[4];
        #pragma unroll
        for (int t = 0; t < 4; t++) {
            af[t] = *(const f16x8*)&As[wm * 64 + t * 16 + l16][quad * 8];
            bf[t] = *(const f16x8*)&Bs[wn * 64 + t * 16 + l16][quad * 8];
        }
        #pragma unroll
        for (int i = 0; i < 4; i++)
            #pragma unroll
            for (int j = 0; j < 4; j++)
                acc[i][j] = __builtin_amdgcn_mfma_f32_16x16x32_f16(af[i], bf[j], acc[i][j], 0, 0, 0);
    }

    const int region = n0 >> 10;
    #pragma unroll
    for (int i = 0; i < 4; i++) {
        const int mb = m0 + wm * 64 + i * 16 + quad * 4;
        #pragma unroll
        for (int j = 0; j < 4; j++) {
            const int n  = n0 + wn * 64 + j * 16 + l16;
            const float bn = bias[n];
            #pragma unroll
            for (int r = 0; r < 4; r++) {
                const int m = mb + r;
                const float v = acc[i][j][r] + bn;
                if (MODE == 0) {
                    Cf[(size_t)m * N + n] = v;
                } else {
                    const int b = m >> 11, s = m & 2047;
                    if (region == 0) {
                        qH[(size_t)m * EMBED + n] = (f16)(v * SCALE_Q);
                    } else if (region == 1) {
                        const int np = n - 1024, hh = np >> 6, d = np & 63;
                        kH[(((size_t)(b * 16 + hh) * SEQ + s) << 6) + d] = (f16)v;
                    } else {
                        const int np = n - 2048, hh = np >> 6, d = np & 63;
                        const int sp = (s & ~31) | ((s & 15) << 1) | ((s >> 4) & 1);
                        vT[((size_t)(b * 16 + hh) * HD + d) * SEQ + sp] = (f16)v;
                    }
                }
            }
        }
    }
}

// ---------------------------------------------------------------------------
// MFMA flash attention v7: single-buffered K/V with phase-ordered async stage.
// Lesson from v6 (dbuf): +dbuf state under the 128-VGPR cap (launch_bounds
// 256,4) spilled to scratch (FETCH/WRITE ~830 MB, 4x slowdown). v7 keeps ONE
// K and ONE V buffer (compile-time LDS addresses only) and instead hides the
// staging latency by ordering phases so each stage is issued right after the
// barrier that frees its buffer and drained by a barrier ~300-500 cy later:
//   QK^T+exp (reads Ks) -> barrier#1 -> STAGE_K(kb+1)   [hides under PV]
//   PV       (reads Vt) -> barrier#2 -> STAGE_V(kb+1)   [hides under next QK^T]
// VGPR pressure is REDUCED vs v5 by time-sharing the fragment block:
// kf is loaded per-t (8 transient) while st0/st1 accumulate (32); kf region
// dies before pf (32) + per-dc vf (8 transient) come alive. Peak ~110 < 128.
// P buffer per-s (both s live across the phase split): LDS 8+8+16 = 32 KB
// -> still 4 blocks/CU (grid-matched residency).
// P store/read uses the 16B-chunk XOR swizzle (chunk ^= row&7) on both sides
// -> 0 bank conflicts (verified in round 2).
// ---------------------------------------------------------------------------
__global__ __launch_bounds__(256, 4) void attn_mfma(const f16* __restrict__ qH,
                                                    const f16* __restrict__ kH,
                                                    const f16* __restrict__ vT,
                                                    f16* __restrict__ ctx) {
    __shared__ alignas(16) f16 Ks[64 * 64];        // 8 KB, swizzled [key][dim]
    __shared__ alignas(16) f16 Vt[64 * 64];        // 8 KB, swizzled [dim][keycol]
    __shared__ alignas(16) f16 Pl[4][2][16 * 64];  // 16 KB, chunk-xor swizzled

    const int tid  = threadIdx.x;
    const int wave = tid >> 6;
    const int lane = tid & 63;
    const int quad = lane >> 4;
    const int l16  = lane & 15;

    // XCD-aware bijective swizzle: grid 1024 % 8 == 0.
    const int bid = (int)blockIdx.x;
    const int swz = (bid & 7) * 128 + (bid >> 3);
    const int qb = swz & 15;
    const int bh = swz >> 4;
    const int h  = bh & 15;
    const int b  = bh >> 4;
    const int q0 = qb * 128 + wave * 32;

    const f16* kB = kH + (size_t)bh * SEQ * HD;
    const f16* vB = vT + (size_t)bh * HD * SEQ;

    // Q fragments (pre-scaled by GEMM1)
    f16x8 qf[2][2];
    #pragma unroll
    for (int s = 0; s < 2; s++) {
        const f16* qp = qH + (size_t)(b * SEQ + q0 + s * 16 + l16) * EMBED + h * HD;
        #pragma unroll
        for (int c = 0; c < 2; c++)
            qf[s][c] = *(const f16x8*)(qp + c * 32 + quad * 8);
    }

    fx4 o[2][4];
    fx4 ls[2];
    #pragma unroll
    for (int s = 0; s < 2; s++) {
        ls[s] = (fx4){0.f, 0.f, 0.f, 0.f};
        #pragma unroll
        for (int dc = 0; dc < 4; dc++)
            o[s][dc] = (fx4){0.f, 0.f, 0.f, 0.f};
    }

    f16x8 ones8;
    #pragma unroll
    for (int j = 0; j < 8; j++) ones8[j] = (f16)1.0f;

    lds_char* ksb = (lds_char*)&Ks[0];
    lds_char* vsb = (lds_char*)&Vt[0];

    // Stage one 64-key K (or V) tile (8 KB). Dest is wave-uniform base +
    // lane*16 (global_load_lds contract); xor swizzle lives in the per-lane
    // GLOBAL source address. Compile-time LDS bases (single buffer each).
    auto STAGE_K = [&](int kb) {
        #pragma unroll
        for (int it = 0; it < 2; it++) {
            const int g  = wave * 2 + it;
            const int c  = g * 64 + lane;
            const int r  = c >> 3;
            const int jl = (c & 7) ^ (r & 7);
            __builtin_amdgcn_global_load_lds(
                (glb_char*)(kB + (size_t)(kb * 64 + r) * HD + jl * 8),
                ksb + g * 1024, 16, 0, 0);
        }
    };
    auto STAGE_V = [&](int kb) {
        #pragma unroll
        for (int it = 0; it < 2; it++) {
            const int g  = wave * 2 + it;
            const int c  = g * 64 + lane;
            const int r  = c >> 3;
            const int jl = (c & 7) ^ (r & 7);
            __builtin_amdgcn_global_load_lds(
                (glb_char*)(vB + (size_t)r * SEQ + kb * 64 + jl * 8),
                vsb + g * 1024, 16, 0, 0);
        }
    };

    STAGE_K(0);
    STAGE_V(0);
    __syncthreads();   // vmcnt(0) drain: tile 0 staged

    for (int kb = 0; kb < SEQ / 64; kb++) {
        // ---- QK^T phase: kf loaded per-t (transient), st0/st1 accumulate ----
        fx4 st0[4], st1[4];
        __builtin_amdgcn_s_setprio(1);
        #pragma unroll
        for (int t = 0; t < 4; t++) {
            const int row = l16 + 16 * t;
            const f16x8 kt0 = *(const f16x8*)&Ks[(row * 8 + ((0 + quad) ^ (row & 7))) * 8];
            const f16x8 kt1 = *(const f16x8*)&Ks[(row * 8 + ((4 + quad) ^ (row & 7))) * 8];
            fx4 z = {0.f, 0.f, 0.f, 0.f};
            st0[t] = __builtin_amdgcn_mfma_f32_16x16x32_f16(qf[0][0], kt0, z, 0, 0, 0);
            st0[t] = __builtin_amdgcn_mfma_f32_16x16x32_f16(qf[0][1], kt1, st0[t], 0, 0, 0);
            st1[t] = __builtin_amdgcn_mfma_f32_16x16x32_f16(qf[1][0], kt0, z, 0, 0, 0);
            st1[t] = __builtin_amdgcn_mfma_f32_16x16x32_f16(qf[1][1], kt1, st1[t], 0, 0, 0);
        }
        __builtin_amdgcn_s_setprio(0);

        // ---- exp2 + packed P store, both s (st dies here) ----
        #pragma unroll
        for (int g = 0; g < 2; g++)
            #pragma unroll
            for (int r = 0; r < 4; r++) {
                const int row = quad * 4 + r;
                const int cc  = (g * 4 + (l16 >> 2)) ^ (row & 7);
                {
                    const float pa = exp2f(st0[2 * g][r]);
                    const float pb = exp2f(st0[2 * g + 1][r]);
                    const f16x2 pk = __builtin_bit_cast(f16x2, __builtin_amdgcn_cvt_pkrtz(pa, pb));
                    *(f16x2*)&Pl[wave][0][row * 64 + cc * 8 + (l16 & 3) * 2] = pk;
                }
                {
                    const float pa = exp2f(st1[2 * g][r]);
                    const float pb = exp2f(st1[2 * g + 1][r]);
                    const f16x2 pk = __builtin_bit_cast(f16x2, __builtin_amdgcn_cvt_pkrtz(pa, pb));
                    *(f16x2*)&Pl[wave][1][row * 64 + cc * 8 + (l16 & 3) * 2] = pk;
                }
            }

        // ---- barrier #1: all waves done reading Ks -> stage K(kb+1) now;
        //      its L2 latency hides under the PV phase below.              ----
        __syncthreads();
        if (kb + 1 < SEQ / 64) STAGE_K(kb + 1);

        // ---- PV phase: pf for both s (32 regs), vf per-dc transient (8) ----
        const f16x8 pf00 = *(const f16x8*)&Pl[wave][0][l16 * 64 + ((0 + quad) ^ (l16 & 7)) * 8];
        const f16x8 pf01 = *(const f16x8*)&Pl[wave][0][l16 * 64 + ((4 + quad) ^ (l16 & 7)) * 8];
        const f16x8 pf10 = *(const f16x8*)&Pl[wave][1][l16 * 64 + ((0 + quad) ^ (l16 & 7)) * 8];
        const f16x8 pf11 = *(const f16x8*)&Pl[wave][1][l16 * 64 + ((4 + quad) ^ (l16 & 7)) * 8];
        __builtin_amdgcn_s_setprio(1);
        #pragma unroll
        for (int dc = 0; dc < 4; dc++) {
            const int row = 16 * dc + l16;
            const f16x8 vf0 = *(const f16x8*)&Vt[(row * 8 + ((0 + quad) ^ (row & 7))) * 8];
            const f16x8 vf1 = *(const f16x8*)&Vt[(row * 8 + ((4 + quad) ^ (row & 7))) * 8];
            o[0][dc] = __builtin_amdgcn_mfma_f32_16x16x32_f16(pf00, vf0, o[0][dc], 0, 0, 0);
            o[0][dc] = __builtin_amdgcn_mfma_f32_16x16x32_f16(pf01, vf1, o[0][dc], 0, 0, 0);
            o[1][dc] = __builtin_amdgcn_mfma_f32_16x16x32_f16(pf10, vf0, o[1][dc], 0, 0, 0);
            o[1][dc] = __builtin_amdgcn_mfma_f32_16x16x32_f16(pf11, vf1, o[1][dc], 0, 0, 0);
        }
        ls[0] = __builtin_amdgcn_mfma_f32_16x16x32_f16(pf00, ones8, ls[0], 0, 0, 0);
        ls[0] = __builtin_amdgcn_mfma_f32_16x16x32_f16(pf01, ones8, ls[0], 0, 0, 0);
        ls[1] = __builtin_amdgcn_mfma_f32_16x16x32_f16(pf10, ones8, ls[1], 0, 0, 0);
        ls[1] = __builtin_amdgcn_mfma_f32_16x16x32_f16(pf11, ones8, ls[1], 0, 0, 0);
        __builtin_amdgcn_s_setprio(0);

        // ---- barrier #2: all waves done reading Vt; drains K(kb+1) stage.
        //      Stage V(kb+1) now; hides under next iter's QK^T+exp.        ----
        __syncthreads();
        if (kb + 1 < SEQ / 64) STAGE_V(kb + 1);
    }

    // ---- normalize + store (row sums already in C-layout) ----
    #pragma unroll
    for (int s = 0; s < 2; s++) {
        #pragma unroll
        for (int r = 0; r < 4; r++) {
            const float inv = 1.0f / ls[s][r];
            const int q = q0 + s * 16 + quad * 4 + r;
            f16* dst = ctx + (size_t)(b * SEQ + q) * EMBED + h * HD;
            #pragma unroll
            for (int dc = 0; dc < 4; dc++)
                dst[dc * 16 + l16] = (f16)(o[s][dc][r] * inv);
        }
    }
}

// ---------------------------------------------------------------------------
extern "C" void kernel_launch(void* const* d_in, const int* in_sizes, int n_in,
                              void* d_out, int out_size, void* d_ws, size_t ws_size,
                              hipStream_t stream) {
    const float* x     = (const float*)d_in[0];
    const float* Wqkv  = (const float*)d_in[1];
    const float* bqkv  = (const float*)d_in[2];
    const float* Wproj = (const float*)d_in[3];
    const float* bproj = (const float*)d_in[4];
    float* out = (float*)d_out;

    // Workspace (f16 elements, 16B-aligned segments), total ~92 MB.
    f16* x_h = (f16*)d_ws;                          // 8M
    f16* qHb = x_h + (size_t)ROWS * EMBED;          // 8M
    f16* kHb = qHb + (size_t)ROWS * EMBED;          // 8M
    f16* vTb = kHb + (size_t)ROWS * EMBED;          // 8M
    f16* ctx = vTb + (size_t)ROWS * EMBED;          // 8M
    f16* Wqt = ctx + (size_t)ROWS * EMBED;          // 3M
    f16* Wpt = Wqt + (size_t)3 * EMBED * EMBED;     // 1M

    // 0) fused conversions (x, Wqkv^T, Wproj^T)
    prep<<<dim3(12288), dim3(256), 0, stream>>>(x, x_h, Wqkv, Wqt, Wproj, Wpt);

    // 1) qkv GEMM with layout-splitting epilogue
    gemm_f16k<1><<<dim3(3 * EMBED / 128, ROWS / 128), dim3(256), 0, stream>>>(
        x_h, Wqt, bqkv, nullptr, qHb, kHb, vTb, ROWS, 3 * EMBED, EMBED);

    // 2) flash attention
    attn_mfma<<<dim3(64 * 16), dim3(256), 0, stream>>>(qHb, kHb, vTb, ctx);

    // 3) out = ctx @ Wproj + bias (fp32)
    gemm_f16k<0><<<dim3(EMBED / 128, ROWS / 128), dim3(256), 0, stream>>>(
        ctx, Wpt, bproj, out, nullptr, nullptr, nullptr, ROWS, EMBED, EMBED);
}

// Round 4
// 305.936 us; speedup vs baseline: 2.2579x; 1.0424x over previous
//
#include <hip/hip_runtime.h>
#include <math.h>

#define EMBED 1024
#define HEADS 16
#define HD    64
#define SEQ   2048
#define BATCH 4
#define ROWS  (BATCH * SEQ)   // 8192

typedef _Float16 f16;
typedef __attribute__((ext_vector_type(8))) _Float16 f16x8;
typedef __attribute__((ext_vector_type(4))) _Float16 f16x4;
typedef __attribute__((ext_vector_type(2))) _Float16 f16x2;
typedef __attribute__((ext_vector_type(4))) float    fx4;

typedef __attribute__((address_space(3))) char  lds_char;
typedef __attribute__((address_space(1))) const char glb_char;

#define SCALE_Q 0.18033688011112042f   // 0.125 * log2(e), folded into Q at GEMM1

// ---------------------------------------------------------------------------
// Fused prep: one dispatch does all three input conversions.
//   blocks [0, 8192)        : x fp32 -> f16 (4 elems/thread)
//   blocks [8192, 11264)    : Wqkv [1024][3072] -> Wqt [3072][1024] f16
//   blocks [11264, 12288)   : Wproj [1024][1024] -> Wpt [1024][1024] f16
// ---------------------------------------------------------------------------
__global__ __launch_bounds__(256) void prep(const float* __restrict__ x,
                                            f16* __restrict__ x_h,
                                            const float* __restrict__ Wqkv,
                                            f16* __restrict__ Wqt,
                                            const float* __restrict__ Wproj,
                                            f16* __restrict__ Wpt) {
    const int blk = blockIdx.x;
    if (blk < 8192) {
        const int i = (blk * 256 + threadIdx.x) * 4;
        const float4 v = *(const float4*)(x + i);
        f16x4 o = {(f16)v.x, (f16)v.y, (f16)v.z, (f16)v.w};
        *(f16x4*)(x_h + i) = o;
        return;
    }
    __shared__ float t[32][33];
    const float* W;
    f16* Wt;
    int N, bx, by;
    if (blk < 8192 + 3072) {
        const int b2 = blk - 8192;
        W = Wqkv; Wt = Wqt; N = 3072; bx = b2 % 96; by = b2 / 96;
    } else {
        const int b2 = blk - 8192 - 3072;
        W = Wproj; Wt = Wpt; N = 1024; bx = b2 % 32; by = b2 / 32;
    }
    const int tx = threadIdx.x & 31, ty = threadIdx.x >> 5;   // 32 x 8
    const int k0 = by * 32, n0 = bx * 32;
    #pragma unroll
    for (int i = 0; i < 4; i++)
        t[ty + i * 8][tx] = W[(size_t)(k0 + ty + i * 8) * N + n0 + tx];
    __syncthreads();
    #pragma unroll
    for (int i = 0; i < 4; i++)
        Wt[(size_t)(n0 + ty + i * 8) * 1024 + k0 + tx] = (f16)t[tx][ty + i * 8];
}

// ---------------------------------------------------------------------------
// f16 MFMA GEMM (m97 structure): 128x128 tile, 256 threads, BK=32.
// MODE 0: C = A@Bt^T + bias, fp32 out (proj GEMM).
// MODE 1: qkv GEMM; epilogue splits by n-region (uniform per block):
//   n<1024  -> Q, scaled by SCALE_Q, layout qH[b][s][h*64+d]
//   n<2048  -> K, layout kH[b][h][s][d]
//   else    -> V, layout vT[b][h][d][perm(s)], perm(s)=(s&~31)|((s&15)<<1)|((s>>4)&1)
// ---------------------------------------------------------------------------
template <int MODE>
__global__ __launch_bounds__(256) void gemm_f16k(const f16* __restrict__ A,
                                                 const f16* __restrict__ Bt,
                                                 const float* __restrict__ bias,
                                                 float* __restrict__ Cf,
                                                 f16* __restrict__ qH,
                                                 f16* __restrict__ kH,
                                                 f16* __restrict__ vT,
                                                 int M, int N, int K) {
    __shared__ alignas(16) f16 As[128][32];
    __shared__ alignas(16) f16 Bs[128][32];
    const int tid  = threadIdx.x;
    const int wave = tid >> 6;
    const int lane = tid & 63;
    const int quad = lane >> 4;
    const int l16  = lane & 15;
    const int m0   = blockIdx.y * 128;
    const int n0   = blockIdx.x * 128;
    const int wm   = wave & 1;
    const int wn   = wave >> 1;

    fx4 acc[4][4];
    #pragma unroll
    for (int i = 0; i < 4; i++)
        #pragma unroll
        for (int j = 0; j < 4; j++)
            acc[i][j] = (fx4){0.f, 0.f, 0.f, 0.f};

    lds_char* asb = (lds_char*)&As[0][0];
    lds_char* bsb = (lds_char*)&Bs[0][0];

    for (int k0 = 0; k0 < K; k0 += 32) {
        __syncthreads();
        #pragma unroll
        for (int r = 0; r < 2; r++) {
            const int g   = r * 4 + wave;
            const int c   = g * 64 + lane;
            const int row = c >> 2;
            const int ko  = (c & 3) * 8;
            __builtin_amdgcn_global_load_lds(
                (glb_char*)(A + (size_t)(m0 + row) * K + k0 + ko),
                asb + g * 1024, 16, 0, 0);
            __builtin_amdgcn_global_load_lds(
                (glb_char*)(Bt + (size_t)(n0 + row) * K + k0 + ko),
                bsb + g * 1024, 16, 0, 0);
        }
        __syncthreads();

        f16x8 af[4], bf[4];
        #pragma unroll
        for (int t = 0; t < 4; t++) {
            af[t] = *(const f16x8*)&As[wm * 64 + t * 16 + l16][quad * 8];
            bf[t] = *(const f16x8*)&Bs[wn * 64 + t * 16 + l16][quad * 8];
        }
        #pragma unroll
        for (int i = 0; i < 4; i++)
            #pragma unroll
            for (int j = 0; j < 4; j++)
                acc[i][j] = __builtin_amdgcn_mfma_f32_16x16x32_f16(af[i], bf[j], acc[i][j], 0, 0, 0);
    }

    const int region = n0 >> 10;
    #pragma unroll
    for (int i = 0; i < 4; i++) {
        const int mb = m0 + wm * 64 + i * 16 + quad * 4;
        #pragma unroll
        for (int j = 0; j < 4; j++) {
            const int n  = n0 + wn * 64 + j * 16 + l16;
            const float bn = bias[n];
            #pragma unroll
            for (int r = 0; r < 4; r++) {
                const int m = mb + r;
                const float v = acc[i][j][r] + bn;
                if (MODE == 0) {
                    Cf[(size_t)m * N + n] = v;
                } else {
                    const int b = m >> 11, s = m & 2047;
                    if (region == 0) {
                        qH[(size_t)m * EMBED + n] = (f16)(v * SCALE_Q);
                    } else if (region == 1) {
                        const int np = n - 1024, hh = np >> 6, d = np & 63;
                        kH[(((size_t)(b * 16 + hh) * SEQ + s) << 6) + d] = (f16)v;
                    } else {
                        const int np = n - 2048, hh = np >> 6, d = np & 63;
                        const int sp = (s & ~31) | ((s & 15) << 1) | ((s >> 4) & 1);
                        vT[((size_t)(b * 16 + hh) * HD + d) * SEQ + sp] = (f16)v;
                    }
                }
            }
        }
    }
}

// ---------------------------------------------------------------------------
// MFMA flash attention v8 = v7 + raw v_exp_f32.
// Round-3 counters: VALUBusy 62% vs MfmaUtil 30% -> VALU-bound. Arithmetic:
// 8400 cy/iter/SIMD x 0.62 / 4 waves / 2cy ~ 650 VALU instrs/wave-iter vs
// ~60 at source level. Diagnosis: exp2f lowers to the OCML __ocml_exp2_f32
// path (denormal-range guard, ~8 VALU each); 32/wave-iter ~ 500+ cy. Fix:
// __builtin_amdgcn_exp2f -> single v_exp_f32 (scores bounded, no denormal /
// overflow range; ~1ulp error << f16 quantization). Everything else is
// byte-identical to v7 (phase-ordered single-buffer staging, 0 conflicts).
// ---------------------------------------------------------------------------
__global__ __launch_bounds__(256, 4) void attn_mfma(const f16* __restrict__ qH,
                                                    const f16* __restrict__ kH,
                                                    const f16* __restrict__ vT,
                                                    f16* __restrict__ ctx) {
    __shared__ alignas(16) f16 Ks[64 * 64];        // 8 KB, swizzled [key][dim]
    __shared__ alignas(16) f16 Vt[64 * 64];        // 8 KB, swizzled [dim][keycol]
    __shared__ alignas(16) f16 Pl[4][2][16 * 64];  // 16 KB, chunk-xor swizzled

    const int tid  = threadIdx.x;
    const int wave = tid >> 6;
    const int lane = tid & 63;
    const int quad = lane >> 4;
    const int l16  = lane & 15;

    // XCD-aware bijective swizzle: grid 1024 % 8 == 0.
    const int bid = (int)blockIdx.x;
    const int swz = (bid & 7) * 128 + (bid >> 3);
    const int qb = swz & 15;
    const int bh = swz >> 4;
    const int h  = bh & 15;
    const int b  = bh >> 4;
    const int q0 = qb * 128 + wave * 32;

    const f16* kB = kH + (size_t)bh * SEQ * HD;
    const f16* vB = vT + (size_t)bh * HD * SEQ;

    // Q fragments (pre-scaled by GEMM1)
    f16x8 qf[2][2];
    #pragma unroll
    for (int s = 0; s < 2; s++) {
        const f16* qp = qH + (size_t)(b * SEQ + q0 + s * 16 + l16) * EMBED + h * HD;
        #pragma unroll
        for (int c = 0; c < 2; c++)
            qf[s][c] = *(const f16x8*)(qp + c * 32 + quad * 8);
    }

    fx4 o[2][4];
    fx4 ls[2];
    #pragma unroll
    for (int s = 0; s < 2; s++) {
        ls[s] = (fx4){0.f, 0.f, 0.f, 0.f};
        #pragma unroll
        for (int dc = 0; dc < 4; dc++)
            o[s][dc] = (fx4){0.f, 0.f, 0.f, 0.f};
    }

    f16x8 ones8;
    #pragma unroll
    for (int j = 0; j < 8; j++) ones8[j] = (f16)1.0f;

    lds_char* ksb = (lds_char*)&Ks[0];
    lds_char* vsb = (lds_char*)&Vt[0];

    // Stage one 64-key K (or V) tile (8 KB). Dest is wave-uniform base +
    // lane*16 (global_load_lds contract); xor swizzle lives in the per-lane
    // GLOBAL source address. Compile-time LDS bases (single buffer each).
    auto STAGE_K = [&](int kb) {
        #pragma unroll
        for (int it = 0; it < 2; it++) {
            const int g  = wave * 2 + it;
            const int c  = g * 64 + lane;
            const int r  = c >> 3;
            const int jl = (c & 7) ^ (r & 7);
            __builtin_amdgcn_global_load_lds(
                (glb_char*)(kB + (size_t)(kb * 64 + r) * HD + jl * 8),
                ksb + g * 1024, 16, 0, 0);
        }
    };
    auto STAGE_V = [&](int kb) {
        #pragma unroll
        for (int it = 0; it < 2; it++) {
            const int g  = wave * 2 + it;
            const int c  = g * 64 + lane;
            const int r  = c >> 3;
            const int jl = (c & 7) ^ (r & 7);
            __builtin_amdgcn_global_load_lds(
                (glb_char*)(vB + (size_t)r * SEQ + kb * 64 + jl * 8),
                vsb + g * 1024, 16, 0, 0);
        }
    };

    STAGE_K(0);
    STAGE_V(0);
    __syncthreads();   // vmcnt(0) drain: tile 0 staged

    for (int kb = 0; kb < SEQ / 64; kb++) {
        // ---- QK^T phase: kf loaded per-t (transient), st0/st1 accumulate ----
        fx4 st0[4], st1[4];
        __builtin_amdgcn_s_setprio(1);
        #pragma unroll
        for (int t = 0; t < 4; t++) {
            const int row = l16 + 16 * t;
            const f16x8 kt0 = *(const f16x8*)&Ks[(row * 8 + ((0 + quad) ^ (row & 7))) * 8];
            const f16x8 kt1 = *(const f16x8*)&Ks[(row * 8 + ((4 + quad) ^ (row & 7))) * 8];
            fx4 z = {0.f, 0.f, 0.f, 0.f};
            st0[t] = __builtin_amdgcn_mfma_f32_16x16x32_f16(qf[0][0], kt0, z, 0, 0, 0);
            st0[t] = __builtin_amdgcn_mfma_f32_16x16x32_f16(qf[0][1], kt1, st0[t], 0, 0, 0);
            st1[t] = __builtin_amdgcn_mfma_f32_16x16x32_f16(qf[1][0], kt0, z, 0, 0, 0);
            st1[t] = __builtin_amdgcn_mfma_f32_16x16x32_f16(qf[1][1], kt1, st1[t], 0, 0, 0);
        }
        __builtin_amdgcn_s_setprio(0);

        // ---- exp2 (raw v_exp_f32) + packed P store, both s (st dies here) ----
        #pragma unroll
        for (int g = 0; g < 2; g++)
            #pragma unroll
            for (int r = 0; r < 4; r++) {
                const int row = quad * 4 + r;
                const int cc  = (g * 4 + (l16 >> 2)) ^ (row & 7);
                {
                    const float pa = __builtin_amdgcn_exp2f(st0[2 * g][r]);
                    const float pb = __builtin_amdgcn_exp2f(st0[2 * g + 1][r]);
                    const f16x2 pk = __builtin_bit_cast(f16x2, __builtin_amdgcn_cvt_pkrtz(pa, pb));
                    *(f16x2*)&Pl[wave][0][row * 64 + cc * 8 + (l16 & 3) * 2] = pk;
                }
                {
                    const float pa = __builtin_amdgcn_exp2f(st1[2 * g][r]);
                    const float pb = __builtin_amdgcn_exp2f(st1[2 * g + 1][r]);
                    const f16x2 pk = __builtin_bit_cast(f16x2, __builtin_amdgcn_cvt_pkrtz(pa, pb));
                    *(f16x2*)&Pl[wave][1][row * 64 + cc * 8 + (l16 & 3) * 2] = pk;
                }
            }

        // ---- barrier #1: all waves done reading Ks -> stage K(kb+1) now;
        //      its L2 latency hides under the PV phase below.              ----
        __syncthreads();
        if (kb + 1 < SEQ / 64) STAGE_K(kb + 1);

        // ---- PV phase: pf for both s (32 regs), vf per-dc transient (8) ----
        const f16x8 pf00 = *(const f16x8*)&Pl[wave][0][l16 * 64 + ((0 + quad) ^ (l16 & 7)) * 8];
        const f16x8 pf01 = *(const f16x8*)&Pl[wave][0][l16 * 64 + ((4 + quad) ^ (l16 & 7)) * 8];
        const f16x8 pf10 = *(const f16x8*)&Pl[wave][1][l16 * 64 + ((0 + quad) ^ (l16 & 7)) * 8];
        const f16x8 pf11 = *(const f16x8*)&Pl[wave][1][l16 * 64 + ((4 + quad) ^ (l16 & 7)) * 8];
        __builtin_amdgcn_s_setprio(1);
        #pragma unroll
        for (int dc = 0; dc < 4; dc++) {
            const int row = 16 * dc + l16;
            const f16x8 vf0 = *(const f16x8*)&Vt[(row * 8 + ((0 + quad) ^ (row & 7))) * 8];
            const f16x8 vf1 = *(const f16x8*)&Vt[(row * 8 + ((4 + quad) ^ (row & 7))) * 8];
            o[0][dc] = __builtin_amdgcn_mfma_f32_16x16x32_f16(pf00, vf0, o[0][dc], 0, 0, 0);
            o[0][dc] = __builtin_amdgcn_mfma_f32_16x16x32_f16(pf01, vf1, o[0][dc], 0, 0, 0);
            o[1][dc] = __builtin_amdgcn_mfma_f32_16x16x32_f16(pf10, vf0, o[1][dc], 0, 0, 0);
            o[1][dc] = __builtin_amdgcn_mfma_f32_16x16x32_f16(pf11, vf1, o[1][dc], 0, 0, 0);
        }
        ls[0] = __builtin_amdgcn_mfma_f32_16x16x32_f16(pf00, ones8, ls[0], 0, 0, 0);
        ls[0] = __builtin_amdgcn_mfma_f32_16x16x32_f16(pf01, ones8, ls[0], 0, 0, 0);
        ls[1] = __builtin_amdgcn_mfma_f32_16x16x32_f16(pf10, ones8, ls[1], 0, 0, 0);
        ls[1] = __builtin_amdgcn_mfma_f32_16x16x32_f16(pf11, ones8, ls[1], 0, 0, 0);
        __builtin_amdgcn_s_setprio(0);

        // ---- barrier #2: all waves done reading Vt; drains K(kb+1) stage.
        //      Stage V(kb+1) now; hides under next iter's QK^T+exp.        ----
        __syncthreads();
        if (kb + 1 < SEQ / 64) STAGE_V(kb + 1);
    }

    // ---- normalize + store (row sums already in C-layout) ----
    #pragma unroll
    for (int s = 0; s < 2; s++) {
        #pragma unroll
        for (int r = 0; r < 4; r++) {
            const float inv = 1.0f / ls[s][r];
            const int q = q0 + s * 16 + quad * 4 + r;
            f16* dst = ctx + (size_t)(b * SEQ + q) * EMBED + h * HD;
            #pragma unroll
            for (int dc = 0; dc < 4; dc++)
                dst[dc * 16 + l16] = (f16)(o[s][dc][r] * inv);
        }
    }
}

// ---------------------------------------------------------------------------
extern "C" void kernel_launch(void* const* d_in, const int* in_sizes, int n_in,
                              void* d_out, int out_size, void* d_ws, size_t ws_size,
                              hipStream_t stream) {
    const float* x     = (const float*)d_in[0];
    const float* Wqkv  = (const float*)d_in[1];
    const float* bqkv  = (const float*)d_in[2];
    const float* Wproj = (const float*)d_in[3];
    const float* bproj = (const float*)d_in[4];
    float* out = (float*)d_out;

    // Workspace (f16 elements, 16B-aligned segments), total ~92 MB.
    f16* x_h = (f16*)d_ws;                          // 8M
    f16* qHb = x_h + (size_t)ROWS * EMBED;          // 8M
    f16* kHb = qHb + (size_t)ROWS * EMBED;          // 8M
    f16* vTb = kHb + (size_t)ROWS * EMBED;          // 8M
    f16* ctx = vTb + (size_t)ROWS * EMBED;          // 8M
    f16* Wqt = ctx + (size_t)ROWS * EMBED;          // 3M
    f16* Wpt = Wqt + (size_t)3 * EMBED * EMBED;     // 1M

    // 0) fused conversions (x, Wqkv^T, Wproj^T)
    prep<<<dim3(12288), dim3(256), 0, stream>>>(x, x_h, Wqkv, Wqt, Wproj, Wpt);

    // 1) qkv GEMM with layout-splitting epilogue
    gemm_f16k<1><<<dim3(3 * EMBED / 128, ROWS / 128), dim3(256), 0, stream>>>(
        x_h, Wqt, bqkv, nullptr, qHb, kHb, vTb, ROWS, 3 * EMBED, EMBED);

    // 2) flash attention
    attn_mfma<<<dim3(64 * 16), dim3(256), 0, stream>>>(qHb, kHb, vTb, ctx);

    // 3) out = ctx @ Wproj + bias (fp32)
    gemm_f16k<0><<<dim3(EMBED / 128, ROWS / 128), dim3(256), 0, stream>>>(
        ctx, Wpt, bproj, out, nullptr, nullptr, nullptr, ROWS, EMBED, EMBED);
}

// Round 5
// 295.783 us; speedup vs baseline: 2.3354x; 1.0343x over previous
//
#include <hip/hip_runtime.h>
#include <math.h>

#define EMBED 1024
#define HEADS 16
#define HD    64
#define SEQ   2048
#define BATCH 4
#define ROWS  (BATCH * SEQ)   // 8192

typedef _Float16 f16;
typedef __attribute__((ext_vector_type(8))) _Float16 f16x8;
typedef __attribute__((ext_vector_type(4))) _Float16 f16x4;
typedef __attribute__((ext_vector_type(2))) _Float16 f16x2;
typedef __attribute__((ext_vector_type(4))) float    fx4;

typedef __attribute__((address_space(3))) char  lds_char;
typedef __attribute__((address_space(1))) const char glb_char;

#define SCALE_Q 0.18033688011112042f   // 0.125 * log2(e), folded into Q at GEMM1

// ---------------------------------------------------------------------------
// Fused prep: one dispatch does all three input conversions.
//   blocks [0, 8192)        : x fp32 -> f16 (4 elems/thread)
//   blocks [8192, 11264)    : Wqkv [1024][3072] -> Wqt [3072][1024] f16
//   blocks [11264, 12288)   : Wproj [1024][1024] -> Wpt [1024][1024] f16
// ---------------------------------------------------------------------------
__global__ __launch_bounds__(256) void prep(const float* __restrict__ x,
                                            f16* __restrict__ x_h,
                                            const float* __restrict__ Wqkv,
                                            f16* __restrict__ Wqt,
                                            const float* __restrict__ Wproj,
                                            f16* __restrict__ Wpt) {
    const int blk = blockIdx.x;
    if (blk < 8192) {
        const int i = (blk * 256 + threadIdx.x) * 4;
        const float4 v = *(const float4*)(x + i);
        f16x4 o = {(f16)v.x, (f16)v.y, (f16)v.z, (f16)v.w};
        *(f16x4*)(x_h + i) = o;
        return;
    }
    __shared__ float t[32][33];
    const float* W;
    f16* Wt;
    int N, bx, by;
    if (blk < 8192 + 3072) {
        const int b2 = blk - 8192;
        W = Wqkv; Wt = Wqt; N = 3072; bx = b2 % 96; by = b2 / 96;
    } else {
        const int b2 = blk - 8192 - 3072;
        W = Wproj; Wt = Wpt; N = 1024; bx = b2 % 32; by = b2 / 32;
    }
    const int tx = threadIdx.x & 31, ty = threadIdx.x >> 5;   // 32 x 8
    const int k0 = by * 32, n0 = bx * 32;
    #pragma unroll
    for (int i = 0; i < 4; i++)
        t[ty + i * 8][tx] = W[(size_t)(k0 + ty + i * 8) * N + n0 + tx];
    __syncthreads();
    #pragma unroll
    for (int i = 0; i < 4; i++)
        Wt[(size_t)(n0 + ty + i * 8) * 1024 + k0 + tx] = (f16)t[tx][ty + i * 8];
}

// ---------------------------------------------------------------------------
// f16 MFMA GEMM v2: 128x128 tile, 256 threads, BK=64, single-buffered LDS
// with phase-split staging (v7-attention pattern) + XOR-swizzled LDS + XCD
// chunked block swizzle.
//  - BK=64: rows are 128 B = 8 x 16 B chunks; physical chunk = logical ^
//    (row&7). Swizzle lives in the per-lane GLOBAL source address of
//    global_load_lds (LDS dest stays linear, wave-uniform base) and in the
//    ds_read index -> conflict-free b128 reads (0-conflict pattern verified
//    in attn kernel). Old [128][32] layout measured 6.29M conflict-cycles.
//  - Per iter: read all frags (ks0+ks1) -> MFMA ks0 -> barrier -> STAGE
//    (next tile, same buffer; hidden under MFMA ks1) -> MFMA ks1 -> barrier.
//    ks1 frags MUST be read before STAGE (ds_read after stage would race the
//    in-flight global->LDS writes). 16 iters instead of 32 -> half the
//    barrier drains.
//  - XCD swizzle: flat block id chunked so each XCD owns an 8-m-block span
//    (A panel 2 MB -> L2-fit per XCD). nwg % 8 == 0 for both call sites.
//  - NO launch_bounds min-waves: frags 64 + acc 64 VGPR needs ~145; a 128
//    cap would spill to scratch (v6 lesson: 830 MB scratch traffic, 4x).
// MODE 0: C = A@Bt^T + bias, fp32 out (proj GEMM).
// MODE 1: qkv GEMM; epilogue splits by n-region (uniform per block):
//   n<1024  -> Q, scaled by SCALE_Q, layout qH[b][s][h*64+d]
//   n<2048  -> K, layout kH[b][h][s][d]
//   else    -> V, layout vT[b][h][d][perm(s)], perm(s)=(s&~31)|((s&15)<<1)|((s>>4)&1)
// ---------------------------------------------------------------------------
template <int MODE>
__global__ __launch_bounds__(256) void gemm_f16k(const f16* __restrict__ A,
                                                 const f16* __restrict__ Bt,
                                                 const float* __restrict__ bias,
                                                 float* __restrict__ Cf,
                                                 f16* __restrict__ qH,
                                                 f16* __restrict__ kH,
                                                 f16* __restrict__ vT,
                                                 int M, int N, int K) {
    __shared__ alignas(16) f16 As[128][64];   // 16 KB, swizzled
    __shared__ alignas(16) f16 Bs[128][64];   // 16 KB, swizzled
    const int tid  = threadIdx.x;
    const int wave = tid >> 6;
    const int lane = tid & 63;
    const int quad = lane >> 4;
    const int l16  = lane & 15;

    // XCD-aware bijective chunk swizzle (requires nwg % 8 == 0).
    const int nwg  = gridDim.x * gridDim.y;
    const int flat = blockIdx.y * gridDim.x + blockIdx.x;
    const int swz  = (flat & 7) * (nwg >> 3) + (flat >> 3);
    const int bx   = swz % gridDim.x;
    const int by   = swz / gridDim.x;
    const int m0   = by * 128;
    const int n0   = bx * 128;
    const int wm   = wave & 1;
    const int wn   = wave >> 1;

    fx4 acc[4][4];
    #pragma unroll
    for (int i = 0; i < 4; i++)
        #pragma unroll
        for (int j = 0; j < 4; j++)
            acc[i][j] = (fx4){0.f, 0.f, 0.f, 0.f};

    lds_char* asb = (lds_char*)&As[0][0];
    lds_char* bsb = (lds_char*)&Bs[0][0];

    // Staging: 4 rounds x (A,B). Group g = it*4+wave covers LDS bytes
    // [g*1024, g*1024+1024); lane's 16B land at g*1024 + lane*16 ->
    // row r = g*8 + (lane>>3), phys chunk = lane&7. Source column chunk =
    // phys ^ (r&7); since r&7 == (lane>>3)&7 this is lane-local.
    const int srow = lane >> 3;                         // row within group
    const int sjl  = ((lane & 7) ^ (srow & 7)) * 8;     // source k-offset (f16)
    auto STAGE = [&](int k0) {
        #pragma unroll
        for (int it = 0; it < 4; it++) {
            const int g = it * 4 + wave;
            const int r = g * 8 + srow;
            __builtin_amdgcn_global_load_lds(
                (glb_char*)(A + (size_t)(m0 + r) * K + k0 + sjl),
                asb + g * 1024, 16, 0, 0);
            __builtin_amdgcn_global_load_lds(
                (glb_char*)(Bt + (size_t)(n0 + r) * K + k0 + sjl),
                bsb + g * 1024, 16, 0, 0);
        }
    };

    STAGE(0);
    __syncthreads();   // vmcnt(0) drain: tile 0 staged

    const int NKB = K >> 6;
    for (int kb = 0; kb < NKB; kb++) {
        // ---- read ALL fragments (both k-substeps) before any overwrite ----
        f16x8 af0[4], af1[4], bf0[4], bf1[4];
        #pragma unroll
        for (int t = 0; t < 4; t++) {
            const int ra = wm * 64 + t * 16 + l16;
            const int rb = wn * 64 + t * 16 + l16;
            af0[t] = *(const f16x8*)&As[ra][((0 + quad) ^ (ra & 7)) * 8];
            af1[t] = *(const f16x8*)&As[ra][((4 + quad) ^ (ra & 7)) * 8];
            bf0[t] = *(const f16x8*)&Bs[rb][((0 + quad) ^ (rb & 7)) * 8];
            bf1[t] = *(const f16x8*)&Bs[rb][((4 + quad) ^ (rb & 7)) * 8];
        }

        // ---- MFMA k-substep 0 ----
        #pragma unroll
        for (int i = 0; i < 4; i++)
            #pragma unroll
            for (int j = 0; j < 4; j++)
                acc[i][j] = __builtin_amdgcn_mfma_f32_16x16x32_f16(af0[i], bf0[j], acc[i][j], 0, 0, 0);

        // ---- barrier: all waves' ds_reads complete -> safe to overwrite ----
        __syncthreads();
        if (kb + 1 < NKB) STAGE((kb + 1) << 6);   // hidden under MFMA ks1

        // ---- MFMA k-substep 1 ----
        #pragma unroll
        for (int i = 0; i < 4; i++)
            #pragma unroll
            for (int j = 0; j < 4; j++)
                acc[i][j] = __builtin_amdgcn_mfma_f32_16x16x32_f16(af1[i], bf1[j], acc[i][j], 0, 0, 0);

        // ---- barrier: drains vmcnt -> staged tile ready for next iter ----
        __syncthreads();
    }

    const int region = n0 >> 10;
    #pragma unroll
    for (int i = 0; i < 4; i++) {
        const int mb = m0 + wm * 64 + i * 16 + quad * 4;
        #pragma unroll
        for (int j = 0; j < 4; j++) {
            const int n  = n0 + wn * 64 + j * 16 + l16;
            const float bn = bias[n];
            #pragma unroll
            for (int r = 0; r < 4; r++) {
                const int m = mb + r;
                const float v = acc[i][j][r] + bn;
                if (MODE == 0) {
                    Cf[(size_t)m * N + n] = v;
                } else {
                    const int b = m >> 11, s = m & 2047;
                    if (region == 0) {
                        qH[(size_t)m * EMBED + n] = (f16)(v * SCALE_Q);
                    } else if (region == 1) {
                        const int np = n - 1024, hh = np >> 6, d = np & 63;
                        kH[(((size_t)(b * 16 + hh) * SEQ + s) << 6) + d] = (f16)v;
                    } else {
                        const int np = n - 2048, hh = np >> 6, d = np & 63;
                        const int sp = (s & ~31) | ((s & 15) << 1) | ((s >> 4) & 1);
                        vT[((size_t)(b * 16 + hh) * HD + d) * SEQ + sp] = (f16)v;
                    }
                }
            }
        }
    }
}

// ---------------------------------------------------------------------------
// MFMA flash attention v8 (unchanged from round 4): single-buffered K/V with
// phase-ordered async stage, raw v_exp_f32 softmax, XOR-swizzled LDS,
// ones-column row sums, XCD swizzle. Round-4: dropped below 102 us.
// ---------------------------------------------------------------------------
__global__ __launch_bounds__(256, 4) void attn_mfma(const f16* __restrict__ qH,
                                                    const f16* __restrict__ kH,
                                                    const f16* __restrict__ vT,
                                                    f16* __restrict__ ctx) {
    __shared__ alignas(16) f16 Ks[64 * 64];        // 8 KB, swizzled [key][dim]
    __shared__ alignas(16) f16 Vt[64 * 64];        // 8 KB, swizzled [dim][keycol]
    __shared__ alignas(16) f16 Pl[4][2][16 * 64];  // 16 KB, chunk-xor swizzled

    const int tid  = threadIdx.x;
    const int wave = tid >> 6;
    const int lane = tid & 63;
    const int quad = lane >> 4;
    const int l16  = lane & 15;

    // XCD-aware bijective swizzle: grid 1024 % 8 == 0.
    const int bid = (int)blockIdx.x;
    const int swz = (bid & 7) * 128 + (bid >> 3);
    const int qb = swz & 15;
    const int bh = swz >> 4;
    const int h  = bh & 15;
    const int b  = bh >> 4;
    const int q0 = qb * 128 + wave * 32;

    const f16* kB = kH + (size_t)bh * SEQ * HD;
    const f16* vB = vT + (size_t)bh * HD * SEQ;

    // Q fragments (pre-scaled by GEMM1)
    f16x8 qf[2][2];
    #pragma unroll
    for (int s = 0; s < 2; s++) {
        const f16* qp = qH + (size_t)(b * SEQ + q0 + s * 16 + l16) * EMBED + h * HD;
        #pragma unroll
        for (int c = 0; c < 2; c++)
            qf[s][c] = *(const f16x8*)(qp + c * 32 + quad * 8);
    }

    fx4 o[2][4];
    fx4 ls[2];
    #pragma unroll
    for (int s = 0; s < 2; s++) {
        ls[s] = (fx4){0.f, 0.f, 0.f, 0.f};
        #pragma unroll
        for (int dc = 0; dc < 4; dc++)
            o[s][dc] = (fx4){0.f, 0.f, 0.f, 0.f};
    }

    f16x8 ones8;
    #pragma unroll
    for (int j = 0; j < 8; j++) ones8[j] = (f16)1.0f;

    lds_char* ksb = (lds_char*)&Ks[0];
    lds_char* vsb = (lds_char*)&Vt[0];

    auto STAGE_K = [&](int kb) {
        #pragma unroll
        for (int it = 0; it < 2; it++) {
            const int g  = wave * 2 + it;
            const int c  = g * 64 + lane;
            const int r  = c >> 3;
            const int jl = (c & 7) ^ (r & 7);
            __builtin_amdgcn_global_load_lds(
                (glb_char*)(kB + (size_t)(kb * 64 + r) * HD + jl * 8),
                ksb + g * 1024, 16, 0, 0);
        }
    };
    auto STAGE_V = [&](int kb) {
        #pragma unroll
        for (int it = 0; it < 2; it++) {
            const int g  = wave * 2 + it;
            const int c  = g * 64 + lane;
            const int r  = c >> 3;
            const int jl = (c & 7) ^ (r & 7);
            __builtin_amdgcn_global_load_lds(
                (glb_char*)(vB + (size_t)r * SEQ + kb * 64 + jl * 8),
                vsb + g * 1024, 16, 0, 0);
        }
    };

    STAGE_K(0);
    STAGE_V(0);
    __syncthreads();   // vmcnt(0) drain: tile 0 staged

    for (int kb = 0; kb < SEQ / 64; kb++) {
        // ---- QK^T phase: kf loaded per-t (transient), st0/st1 accumulate ----
        fx4 st0[4], st1[4];
        __builtin_amdgcn_s_setprio(1);
        #pragma unroll
        for (int t = 0; t < 4; t++) {
            const int row = l16 + 16 * t;
            const f16x8 kt0 = *(const f16x8*)&Ks[(row * 8 + ((0 + quad) ^ (row & 7))) * 8];
            const f16x8 kt1 = *(const f16x8*)&Ks[(row * 8 + ((4 + quad) ^ (row & 7))) * 8];
            fx4 z = {0.f, 0.f, 0.f, 0.f};
            st0[t] = __builtin_amdgcn_mfma_f32_16x16x32_f16(qf[0][0], kt0, z, 0, 0, 0);
            st0[t] = __builtin_amdgcn_mfma_f32_16x16x32_f16(qf[0][1], kt1, st0[t], 0, 0, 0);
            st1[t] = __builtin_amdgcn_mfma_f32_16x16x32_f16(qf[1][0], kt0, z, 0, 0, 0);
            st1[t] = __builtin_amdgcn_mfma_f32_16x16x32_f16(qf[1][1], kt1, st1[t], 0, 0, 0);
        }
        __builtin_amdgcn_s_setprio(0);

        // ---- exp2 (raw v_exp_f32) + packed P store, both s (st dies here) ----
        #pragma unroll
        for (int g = 0; g < 2; g++)
            #pragma unroll
            for (int r = 0; r < 4; r++) {
                const int row = quad * 4 + r;
                const int cc  = (g * 4 + (l16 >> 2)) ^ (row & 7);
                {
                    const float pa = __builtin_amdgcn_exp2f(st0[2 * g][r]);
                    const float pb = __builtin_amdgcn_exp2f(st0[2 * g + 1][r]);
                    const f16x2 pk = __builtin_bit_cast(f16x2, __builtin_amdgcn_cvt_pkrtz(pa, pb));
                    *(f16x2*)&Pl[wave][0][row * 64 + cc * 8 + (l16 & 3) * 2] = pk;
                }
                {
                    const float pa = __builtin_amdgcn_exp2f(st1[2 * g][r]);
                    const float pb = __builtin_amdgcn_exp2f(st1[2 * g + 1][r]);
                    const f16x2 pk = __builtin_bit_cast(f16x2, __builtin_amdgcn_cvt_pkrtz(pa, pb));
                    *(f16x2*)&Pl[wave][1][row * 64 + cc * 8 + (l16 & 3) * 2] = pk;
                }
            }

        // ---- barrier #1: all waves done reading Ks -> stage K(kb+1) now;
        //      its L2 latency hides under the PV phase below.              ----
        __syncthreads();
        if (kb + 1 < SEQ / 64) STAGE_K(kb + 1);

        // ---- PV phase: pf for both s (32 regs), vf per-dc transient (8) ----
        const f16x8 pf00 = *(const f16x8*)&Pl[wave][0][l16 * 64 + ((0 + quad) ^ (l16 & 7)) * 8];
        const f16x8 pf01 = *(const f16x8*)&Pl[wave][0][l16 * 64 + ((4 + quad) ^ (l16 & 7)) * 8];
        const f16x8 pf10 = *(const f16x8*)&Pl[wave][1][l16 * 64 + ((0 + quad) ^ (l16 & 7)) * 8];
        const f16x8 pf11 = *(const f16x8*)&Pl[wave][1][l16 * 64 + ((4 + quad) ^ (l16 & 7)) * 8];
        __builtin_amdgcn_s_setprio(1);
        #pragma unroll
        for (int dc = 0; dc < 4; dc++) {
            const int row = 16 * dc + l16;
            const f16x8 vf0 = *(const f16x8*)&Vt[(row * 8 + ((0 + quad) ^ (row & 7))) * 8];
            const f16x8 vf1 = *(const f16x8*)&Vt[(row * 8 + ((4 + quad) ^ (row & 7))) * 8];
            o[0][dc] = __builtin_amdgcn_mfma_f32_16x16x32_f16(pf00, vf0, o[0][dc], 0, 0, 0);
            o[0][dc] = __builtin_amdgcn_mfma_f32_16x16x32_f16(pf01, vf1, o[0][dc], 0, 0, 0);
            o[1][dc] = __builtin_amdgcn_mfma_f32_16x16x32_f16(pf10, vf0, o[1][dc], 0, 0, 0);
            o[1][dc] = __builtin_amdgcn_mfma_f32_16x16x32_f16(pf11, vf1, o[1][dc], 0, 0, 0);
        }
        ls[0] = __builtin_amdgcn_mfma_f32_16x16x32_f16(pf00, ones8, ls[0], 0, 0, 0);
        ls[0] = __builtin_amdgcn_mfma_f32_16x16x32_f16(pf01, ones8, ls[0], 0, 0, 0);
        ls[1] = __builtin_amdgcn_mfma_f32_16x16x32_f16(pf10, ones8, ls[1], 0, 0, 0);
        ls[1] = __builtin_amdgcn_mfma_f32_16x16x32_f16(pf11, ones8, ls[1], 0, 0, 0);
        __builtin_amdgcn_s_setprio(0);

        // ---- barrier #2: all waves done reading Vt; drains K(kb+1) stage.
        //      Stage V(kb+1) now; hides under next iter's QK^T+exp.        ----
        __syncthreads();
        if (kb + 1 < SEQ / 64) STAGE_V(kb + 1);
    }

    // ---- normalize + store (row sums already in C-layout) ----
    #pragma unroll
    for (int s = 0; s < 2; s++) {
        #pragma unroll
        for (int r = 0; r < 4; r++) {
            const float inv = 1.0f / ls[s][r];
            const int q = q0 + s * 16 + quad * 4 + r;
            f16* dst = ctx + (size_t)(b * SEQ + q) * EMBED + h * HD;
            #pragma unroll
            for (int dc = 0; dc < 4; dc++)
                dst[dc * 16 + l16] = (f16)(o[s][dc][r] * inv);
        }
    }
}

// ---------------------------------------------------------------------------
extern "C" void kernel_launch(void* const* d_in, const int* in_sizes, int n_in,
                              void* d_out, int out_size, void* d_ws, size_t ws_size,
                              hipStream_t stream) {
    const float* x     = (const float*)d_in[0];
    const float* Wqkv  = (const float*)d_in[1];
    const float* bqkv  = (const float*)d_in[2];
    const float* Wproj = (const float*)d_in[3];
    const float* bproj = (const float*)d_in[4];
    float* out = (float*)d_out;

    // Workspace (f16 elements, 16B-aligned segments), total ~92 MB.
    f16* x_h = (f16*)d_ws;                          // 8M
    f16* qHb = x_h + (size_t)ROWS * EMBED;          // 8M
    f16* kHb = qHb + (size_t)ROWS * EMBED;          // 8M
    f16* vTb = kHb + (size_t)ROWS * EMBED;          // 8M
    f16* ctx = vTb + (size_t)ROWS * EMBED;          // 8M
    f16* Wqt = ctx + (size_t)ROWS * EMBED;          // 3M
    f16* Wpt = Wqt + (size_t)3 * EMBED * EMBED;     // 1M

    // 0) fused conversions (x, Wqkv^T, Wproj^T)
    prep<<<dim3(12288), dim3(256), 0, stream>>>(x, x_h, Wqkv, Wqt, Wproj, Wpt);

    // 1) qkv GEMM with layout-splitting epilogue
    gemm_f16k<1><<<dim3(3 * EMBED / 128, ROWS / 128), dim3(256), 0, stream>>>(
        x_h, Wqt, bqkv, nullptr, qHb, kHb, vTb, ROWS, 3 * EMBED, EMBED);

    // 2) flash attention
    attn_mfma<<<dim3(64 * 16), dim3(256), 0, stream>>>(qHb, kHb, vTb, ctx);

    // 3) out = ctx @ Wproj + bias (fp32)
    gemm_f16k<0><<<dim3(EMBED / 128, ROWS / 128), dim3(256), 0, stream>>>(
        ctx, Wpt, bproj, out, nullptr, nullptr, nullptr, ROWS, EMBED, EMBED);
}

// Round 7
// 282.661 us; speedup vs baseline: 2.4438x; 1.0464x over previous
//
#include <hip/hip_runtime.h>
#include <math.h>

#define EMBED 1024
#define HEADS 16
#define HD    64
#define SEQ   2048
#define BATCH 4
#define ROWS  (BATCH * SEQ)   // 8192

typedef _Float16 f16;
typedef __attribute__((ext_vector_type(8))) _Float16 f16x8;
typedef __attribute__((ext_vector_type(4))) _Float16 f16x4;
typedef __attribute__((ext_vector_type(2))) _Float16 f16x2;
typedef __attribute__((ext_vector_type(4))) float    fx4;

typedef __attribute__((address_space(3))) char  lds_char;
typedef __attribute__((address_space(1))) const char glb_char;

#define SCALE_Q 0.18033688011112042f   // 0.125 * log2(e), folded into Q at GEMM1

// ---------------------------------------------------------------------------
// Fused prep (unchanged).
// ---------------------------------------------------------------------------
__global__ __launch_bounds__(256) void prep(const float* __restrict__ x,
                                            f16* __restrict__ x_h,
                                            const float* __restrict__ Wqkv,
                                            f16* __restrict__ Wqt,
                                            const float* __restrict__ Wproj,
                                            f16* __restrict__ Wpt) {
    const int blk = blockIdx.x;
    if (blk < 8192) {
        const int i = (blk * 256 + threadIdx.x) * 4;
        const float4 v = *(const float4*)(x + i);
        f16x4 o = {(f16)v.x, (f16)v.y, (f16)v.z, (f16)v.w};
        *(f16x4*)(x_h + i) = o;
        return;
    }
    __shared__ float t[32][33];
    const float* W;
    f16* Wt;
    int N, bx, by;
    if (blk < 8192 + 3072) {
        const int b2 = blk - 8192;
        W = Wqkv; Wt = Wqt; N = 3072; bx = b2 % 96; by = b2 / 96;
    } else {
        const int b2 = blk - 8192 - 3072;
        W = Wproj; Wt = Wpt; N = 1024; bx = b2 % 32; by = b2 / 32;
    }
    const int tx = threadIdx.x & 31, ty = threadIdx.x >> 5;   // 32 x 8
    const int k0 = by * 32, n0 = bx * 32;
    #pragma unroll
    for (int i = 0; i < 4; i++)
        t[ty + i * 8][tx] = W[(size_t)(k0 + ty + i * 8) * N + n0 + tx];
    __syncthreads();
    #pragma unroll
    for (int i = 0; i < 4; i++)
        Wt[(size_t)(n0 + ty + i * 8) * 1024 + k0 + tx] = (f16)t[tx][ty + i * 8];
}

// ---------------------------------------------------------------------------
// f16 MFMA GEMM v3: static double-buffered LDS, one barrier per K-tile.
// Round-5 evidence: BK64+swizzle (0 conflicts) == BK32+8-way (6.3M) in time
// -> LDS conflicts irrelevant; gemm0 (coalesced epi, 1/3 FLOPs, 2 blk/CU)
// nearly as slow as gemm1 -> stage->drain latency + TLP deficit is the cost.
// v3 structure per tile t: COMPUTE(buf[t&1]) -> sync -> STAGE(buf[t&1], t+2).
// The stage for t+2 is in flight across ALL of tile t+1's compute (~600-900cy)
// before the sync that drains it; 1 sync/tile instead of 2. Buffers are
// STATICALLY named (As0/As1/Bs0/Bs1) - no runtime LDS indexing, no VGPR cap
// (v6 spill lesson), plain BK=32 linear layout (v1's verified staging math).
// MODE 0: BM=64 (acc[2][4]) -> grid 1024 blocks = 4/CU (TLP for the
//         latency-bound small-N dispatch). C = A@Bt^T + bias, fp32.
// MODE 1: BM=128 (acc[4][4]); epilogue by n-region: Q direct, K direct,
//         V via LDS-bounce: the old 64 scatter-stores (16 cache lines each)
//         become LDS writes + 8 coalesced 16B stores/thread, reusing the
//         32KB smem after the final barrier. Chunk-XOR (sp>>3)^(n&15) on
//         both LDS sides keeps write ~2-way and read vectorizable.
// ---------------------------------------------------------------------------
template <int MODE>
__global__ __launch_bounds__(256) void gemm_f16k(const f16* __restrict__ A,
                                                 const f16* __restrict__ Bt,
                                                 const float* __restrict__ bias,
                                                 float* __restrict__ Cf,
                                                 f16* __restrict__ qH,
                                                 f16* __restrict__ kH,
                                                 f16* __restrict__ vT,
                                                 int M, int N, int K) {
    constexpr int MI  = (MODE == 0) ? 2 : 4;      // acc rows per wave
    constexpr int BM  = MI * 32;                   // 64 or 128
    constexpr int AEL = BM * 32;                   // As f16 elements per buffer
    constexpr int BEL = 128 * 32;                  // Bs f16 elements per buffer
    __shared__ alignas(16) f16 smem[2 * (AEL + BEL)];   // 24 KB / 32 KB

    f16 (*As0)[32] = (f16(*)[32])(smem);
    f16 (*As1)[32] = (f16(*)[32])(smem + AEL);
    f16 (*Bs0)[32] = (f16(*)[32])(smem + 2 * AEL);
    f16 (*Bs1)[32] = (f16(*)[32])(smem + 2 * AEL + BEL);
    lds_char* a0b = (lds_char*)smem;
    lds_char* a1b = (lds_char*)smem + AEL * 2;
    lds_char* b0b = (lds_char*)smem + 4 * AEL;
    lds_char* b1b = (lds_char*)smem + 4 * AEL + BEL * 2;

    const int tid  = threadIdx.x;
    const int wave = tid >> 6;
    const int lane = tid & 63;
    const int quad = lane >> 4;
    const int l16  = lane & 15;

    // XCD-aware bijective chunk swizzle (nwg % 8 == 0 at both call sites).
    const int nwg  = gridDim.x * gridDim.y;
    const int flat = blockIdx.y * gridDim.x + blockIdx.x;
    const int swz  = (flat & 7) * (nwg >> 3) + (flat >> 3);
    const int bx   = swz % gridDim.x;
    const int by   = swz / gridDim.x;
    const int m0   = by * BM;
    const int n0   = bx * 128;
    const int wm   = wave & 1;
    const int wn   = wave >> 1;

    fx4 acc[MI][4];
    #pragma unroll
    for (int i = 0; i < MI; i++)
        #pragma unroll
        for (int j = 0; j < 4; j++)
            acc[i][j] = (fx4){0.f, 0.f, 0.f, 0.f};

    // v1's verified staging math: group g = 16 rows x 64B (1 KB); lane's 16B
    // at row g*16 + (lane>>2), col (lane&3)*8 f16. LDS dst wave-uniform base.
    const int grow = lane >> 2;
    const int gcol = (lane & 3) * 8;
    auto STAGE = [&](lds_char* asb, lds_char* bsb, int k0) {
        if (MODE == 1) {
            #pragma unroll
            for (int r = 0; r < 2; r++) {
                const int g = r * 4 + wave;
                __builtin_amdgcn_global_load_lds(
                    (glb_char*)(A + (size_t)(m0 + g * 16 + grow) * K + k0 + gcol),
                    asb + g * 1024, 16, 0, 0);
                __builtin_amdgcn_global_load_lds(
                    (glb_char*)(Bt + (size_t)(n0 + g * 16 + grow) * K + k0 + gcol),
                    bsb + g * 1024, 16, 0, 0);
            }
        } else {
            const int ga = wave;                       // A: 4 groups (64 rows)
            __builtin_amdgcn_global_load_lds(
                (glb_char*)(A + (size_t)(m0 + ga * 16 + grow) * K + k0 + gcol),
                asb + ga * 1024, 16, 0, 0);
            #pragma unroll
            for (int r = 0; r < 2; r++) {
                const int g = r * 4 + wave;
                __builtin_amdgcn_global_load_lds(
                    (glb_char*)(Bt + (size_t)(n0 + g * 16 + grow) * K + k0 + gcol),
                    bsb + g * 1024, 16, 0, 0);
            }
        }
    };

    auto COMPUTE = [&](f16 (*As)[32], f16 (*Bs)[32]) {
        f16x8 af[MI], bf[4];
        #pragma unroll
        for (int i = 0; i < MI; i++)
            af[i] = *(const f16x8*)&As[wm * (MI * 16) + i * 16 + l16][quad * 8];
        #pragma unroll
        for (int j = 0; j < 4; j++)
            bf[j] = *(const f16x8*)&Bs[wn * 64 + j * 16 + l16][quad * 8];
        __builtin_amdgcn_s_setprio(1);
        #pragma unroll
        for (int i = 0; i < MI; i++)
            #pragma unroll
            for (int j = 0; j < 4; j++)
                acc[i][j] = __builtin_amdgcn_mfma_f32_16x16x32_f16(af[i], bf[j], acc[i][j], 0, 0, 0);
        __builtin_amdgcn_s_setprio(0);
    };

    STAGE(a0b, b0b, 0);
    __syncthreads();                 // tile 0 resident
    STAGE(a1b, b1b, 32);             // tile 1 in flight

    const int NT = K >> 5;           // 32 tiles
    for (int t = 0; t < NT; t += 2) {
        COMPUTE(As0, Bs0);
        __syncthreads();             // drains tile t+1; frees buf0
        if (t + 2 < NT) STAGE(a0b, b0b, (t + 2) * 32);
        COMPUTE(As1, Bs1);
        __syncthreads();             // drains tile t+2; frees buf1
        if (t + 3 < NT) STAGE(a1b, b1b, (t + 3) * 32);
    }

    const int region = (MODE == 1) ? (n0 >> 10) : 0;

    if (MODE == 1 && region == 2) {
        // ---- V epilogue via LDS bounce (block-uniform branch) ----
        // Write acc as f16 into smem[nloc][sp] with chunk-XOR swizzle.
        const int b  = m0 >> 11;
        const int s0 = m0 & 2047;
        #pragma unroll
        for (int i = 0; i < MI; i++) {
            #pragma unroll
            for (int j = 0; j < 4; j++) {
                const int nloc = wn * 64 + j * 16 + l16;
                const float bn = bias[n0 + nloc];
                #pragma unroll
                for (int r = 0; r < 4; r++) {
                    const int sloc = wm * 64 + i * 16 + quad * 4 + r;
                    const int sp   = (sloc & ~31) | ((sloc & 15) << 1) | ((sloc >> 4) & 1);
                    const int phys = (sp >> 3) ^ (nloc & 15);
                    smem[nloc * 128 + phys * 8 + (sp & 7)] = (f16)(acc[i][j][r] + bn);
                }
            }
        }
        __syncthreads();
        // Read back row-wise (8 x b128) and store coalesced 16B runs.
        const int nl = tid >> 1;                 // 0..127 local n
        const int hf = tid & 1;                  // s half
        const int np0 = n0 - 2048;
        f16* dst = vT + ((size_t)(b * 16 + ((np0 + nl) >> 6)) * HD + (nl & 63)) * SEQ
                      + s0 + hf * 64;
        #pragma unroll
        for (int ch = 0; ch < 8; ch++) {
            const int lc   = hf * 8 + ch;
            const int phys = lc ^ (nl & 15);
            const f16x8 v  = *(const f16x8*)&smem[nl * 128 + phys * 8];
            *(f16x8*)(dst + ch * 8) = v;
        }
        return;
    }

    #pragma unroll
    for (int i = 0; i < MI; i++) {
        const int mb = m0 + wm * (MI * 16) + i * 16 + quad * 4;
        #pragma unroll
        for (int j = 0; j < 4; j++) {
            const int n  = n0 + wn * 64 + j * 16 + l16;
            const float bn = bias[n];
            #pragma unroll
            for (int r = 0; r < 4; r++) {
                const int m = mb + r;
                const float v = acc[i][j][r] + bn;
                if (MODE == 0) {
                    Cf[(size_t)m * N + n] = v;
                } else {
                    const int b = m >> 11, s = m & 2047;
                    if (region == 0) {
                        qH[(size_t)m * EMBED + n] = (f16)(v * SCALE_Q);
                    } else {   // region 1: K
                        const int np = n - 1024, hh = np >> 6, d = np & 63;
                        kH[(((size_t)(b * 16 + hh) * SEQ + s) << 6) + d] = (f16)v;
                    }
                }
            }
        }
    }
}

// ---------------------------------------------------------------------------
// MFMA flash attention v8 (unchanged from round 4/5): single-buffered K/V,
// phase-ordered async stage, raw v_exp_f32 softmax, XOR-swizzled LDS,
// ones-column row sums, XCD swizzle. ~95us.
// ---------------------------------------------------------------------------
__global__ __launch_bounds__(256, 4) void attn_mfma(const f16* __restrict__ qH,
                                                    const f16* __restrict__ kH,
                                                    const f16* __restrict__ vT,
                                                    f16* __restrict__ ctx) {
    __shared__ alignas(16) f16 Ks[64 * 64];        // 8 KB, swizzled [key][dim]
    __shared__ alignas(16) f16 Vt[64 * 64];        // 8 KB, swizzled [dim][keycol]
    __shared__ alignas(16) f16 Pl[4][2][16 * 64];  // 16 KB, chunk-xor swizzled

    const int tid  = threadIdx.x;
    const int wave = tid >> 6;
    const int lane = tid & 63;
    const int quad = lane >> 4;
    const int l16  = lane & 15;

    const int bid = (int)blockIdx.x;
    const int swz = (bid & 7) * 128 + (bid >> 3);
    const int qb = swz & 15;
    const int bh = swz >> 4;
    const int h  = bh & 15;
    const int b  = bh >> 4;
    const int q0 = qb * 128 + wave * 32;

    const f16* kB = kH + (size_t)bh * SEQ * HD;
    const f16* vB = vT + (size_t)bh * HD * SEQ;

    f16x8 qf[2][2];
    #pragma unroll
    for (int s = 0; s < 2; s++) {
        const f16* qp = qH + (size_t)(b * SEQ + q0 + s * 16 + l16) * EMBED + h * HD;
        #pragma unroll
        for (int c = 0; c < 2; c++)
            qf[s][c] = *(const f16x8*)(qp + c * 32 + quad * 8);
    }

    fx4 o[2][4];
    fx4 ls[2];
    #pragma unroll
    for (int s = 0; s < 2; s++) {
        ls[s] = (fx4){0.f, 0.f, 0.f, 0.f};
        #pragma unroll
        for (int dc = 0; dc < 4; dc++)
            o[s][dc] = (fx4){0.f, 0.f, 0.f, 0.f};
    }

    f16x8 ones8;
    #pragma unroll
    for (int j = 0; j < 8; j++) ones8[j] = (f16)1.0f;

    lds_char* ksb = (lds_char*)&Ks[0];
    lds_char* vsb = (lds_char*)&Vt[0];

    auto STAGE_K = [&](int kb) {
        #pragma unroll
        for (int it = 0; it < 2; it++) {
            const int g  = wave * 2 + it;
            const int c  = g * 64 + lane;
            const int r  = c >> 3;
            const int jl = (c & 7) ^ (r & 7);
            __builtin_amdgcn_global_load_lds(
                (glb_char*)(kB + (size_t)(kb * 64 + r) * HD + jl * 8),
                ksb + g * 1024, 16, 0, 0);
        }
    };
    auto STAGE_V = [&](int kb) {
        #pragma unroll
        for (int it = 0; it < 2; it++) {
            const int g  = wave * 2 + it;
            const int c  = g * 64 + lane;
            const int r  = c >> 3;
            const int jl = (c & 7) ^ (r & 7);
            __builtin_amdgcn_global_load_lds(
                (glb_char*)(vB + (size_t)r * SEQ + kb * 64 + jl * 8),
                vsb + g * 1024, 16, 0, 0);
        }
    };

    STAGE_K(0);
    STAGE_V(0);
    __syncthreads();

    for (int kb = 0; kb < SEQ / 64; kb++) {
        fx4 st0[4], st1[4];
        __builtin_amdgcn_s_setprio(1);
        #pragma unroll
        for (int t = 0; t < 4; t++) {
            const int row = l16 + 16 * t;
            const f16x8 kt0 = *(const f16x8*)&Ks[(row * 8 + ((0 + quad) ^ (row & 7))) * 8];
            const f16x8 kt1 = *(const f16x8*)&Ks[(row * 8 + ((4 + quad) ^ (row & 7))) * 8];
            fx4 z = {0.f, 0.f, 0.f, 0.f};
            st0[t] = __builtin_amdgcn_mfma_f32_16x16x32_f16(qf[0][0], kt0, z, 0, 0, 0);
            st0[t] = __builtin_amdgcn_mfma_f32_16x16x32_f16(qf[0][1], kt1, st0[t], 0, 0, 0);
            st1[t] = __builtin_amdgcn_mfma_f32_16x16x32_f16(qf[1][0], kt0, z, 0, 0, 0);
            st1[t] = __builtin_amdgcn_mfma_f32_16x16x32_f16(qf[1][1], kt1, st1[t], 0, 0, 0);
        }
        __builtin_amdgcn_s_setprio(0);

        #pragma unroll
        for (int g = 0; g < 2; g++)
            #pragma unroll
            for (int r = 0; r < 4; r++) {
                const int row = quad * 4 + r;
                const int cc  = (g * 4 + (l16 >> 2)) ^ (row & 7);
                {
                    const float pa = __builtin_amdgcn_exp2f(st0[2 * g][r]);
                    const float pb = __builtin_amdgcn_exp2f(st0[2 * g + 1][r]);
                    const f16x2 pk = __builtin_bit_cast(f16x2, __builtin_amdgcn_cvt_pkrtz(pa, pb));
                    *(f16x2*)&Pl[wave][0][row * 64 + cc * 8 + (l16 & 3) * 2] = pk;
                }
                {
                    const float pa = __builtin_amdgcn_exp2f(st1[2 * g][r]);
                    const float pb = __builtin_amdgcn_exp2f(st1[2 * g + 1][r]);
                    const f16x2 pk = __builtin_bit_cast(f16x2, __builtin_amdgcn_cvt_pkrtz(pa, pb));
                    *(f16x2*)&Pl[wave][1][row * 64 + cc * 8 + (l16 & 3) * 2] = pk;
                }
            }

        __syncthreads();
        if (kb + 1 < SEQ / 64) STAGE_K(kb + 1);

        const f16x8 pf00 = *(const f16x8*)&Pl[wave][0][l16 * 64 + ((0 + quad) ^ (l16 & 7)) * 8];
        const f16x8 pf01 = *(const f16x8*)&Pl[wave][0][l16 * 64 + ((4 + quad) ^ (l16 & 7)) * 8];
        const f16x8 pf10 = *(const f16x8*)&Pl[wave][1][l16 * 64 + ((0 + quad) ^ (l16 & 7)) * 8];
        const f16x8 pf11 = *(const f16x8*)&Pl[wave][1][l16 * 64 + ((4 + quad) ^ (l16 & 7)) * 8];
        __builtin_amdgcn_s_setprio(1);
        #pragma unroll
        for (int dc = 0; dc < 4; dc++) {
            const int row = 16 * dc + l16;
            const f16x8 vf0 = *(const f16x8*)&Vt[(row * 8 + ((0 + quad) ^ (row & 7))) * 8];
            const f16x8 vf1 = *(const f16x8*)&Vt[(row * 8 + ((4 + quad) ^ (row & 7))) * 8];
            o[0][dc] = __builtin_amdgcn_mfma_f32_16x16x32_f16(pf00, vf0, o[0][dc], 0, 0, 0);
            o[0][dc] = __builtin_amdgcn_mfma_f32_16x16x32_f16(pf01, vf1, o[0][dc], 0, 0, 0);
            o[1][dc] = __builtin_amdgcn_mfma_f32_16x16x32_f16(pf10, vf0, o[1][dc], 0, 0, 0);
            o[1][dc] = __builtin_amdgcn_mfma_f32_16x16x32_f16(pf11, vf1, o[1][dc], 0, 0, 0);
        }
        ls[0] = __builtin_amdgcn_mfma_f32_16x16x32_f16(pf00, ones8, ls[0], 0, 0, 0);
        ls[0] = __builtin_amdgcn_mfma_f32_16x16x32_f16(pf01, ones8, ls[0], 0, 0, 0);
        ls[1] = __builtin_amdgcn_mfma_f32_16x16x32_f16(pf10, ones8, ls[1], 0, 0, 0);
        ls[1] = __builtin_amdgcn_mfma_f32_16x16x32_f16(pf11, ones8, ls[1], 0, 0, 0);
        __builtin_amdgcn_s_setprio(0);

        __syncthreads();
        if (kb + 1 < SEQ / 64) STAGE_V(kb + 1);
    }

    #pragma unroll
    for (int s = 0; s < 2; s++) {
        #pragma unroll
        for (int r = 0; r < 4; r++) {
            const float inv = 1.0f / ls[s][r];
            const int q = q0 + s * 16 + quad * 4 + r;
            f16* dst = ctx + (size_t)(b * SEQ + q) * EMBED + h * HD;
            #pragma unroll
            for (int dc = 0; dc < 4; dc++)
                dst[dc * 16 + l16] = (f16)(o[s][dc][r] * inv);
        }
    }
}

// ---------------------------------------------------------------------------
extern "C" void kernel_launch(void* const* d_in, const int* in_sizes, int n_in,
                              void* d_out, int out_size, void* d_ws, size_t ws_size,
                              hipStream_t stream) {
    const float* x     = (const float*)d_in[0];
    const float* Wqkv  = (const float*)d_in[1];
    const float* bqkv  = (const float*)d_in[2];
    const float* Wproj = (const float*)d_in[3];
    const float* bproj = (const float*)d_in[4];
    float* out = (float*)d_out;

    f16* x_h = (f16*)d_ws;                          // 8M
    f16* qHb = x_h + (size_t)ROWS * EMBED;          // 8M
    f16* kHb = qHb + (size_t)ROWS * EMBED;          // 8M
    f16* vTb = kHb + (size_t)ROWS * EMBED;          // 8M
    f16* ctx = vTb + (size_t)ROWS * EMBED;          // 8M
    f16* Wqt = ctx + (size_t)ROWS * EMBED;          // 3M
    f16* Wpt = Wqt + (size_t)3 * EMBED * EMBED;     // 1M

    // 0) fused conversions (x, Wqkv^T, Wproj^T)
    prep<<<dim3(12288), dim3(256), 0, stream>>>(x, x_h, Wqkv, Wqt, Wproj, Wpt);

    // 1) qkv GEMM (BM=128): grid (24, 64) = 1536 blocks
    gemm_f16k<1><<<dim3(3 * EMBED / 128, ROWS / 128), dim3(256), 0, stream>>>(
        x_h, Wqt, bqkv, nullptr, qHb, kHb, vTb, ROWS, 3 * EMBED, EMBED);

    // 2) flash attention
    attn_mfma<<<dim3(64 * 16), dim3(256), 0, stream>>>(qHb, kHb, vTb, ctx);

    // 3) out = ctx @ Wproj + bias (BM=64): grid (8, 128) = 1024 blocks
    gemm_f16k<0><<<dim3(EMBED / 128, ROWS / 64), dim3(256), 0, stream>>>(
        ctx, Wpt, bproj, out, nullptr, nullptr, nullptr, ROWS, EMBED, EMBED);
}

// Round 8
// 269.424 us; speedup vs baseline: 2.5639x; 1.0491x over previous
//
#include <hip/hip_runtime.h>
#include <math.h>

#define EMBED 1024
#define HEADS 16
#define HD    64
#define SEQ   2048
#define BATCH 4
#define ROWS  (BATCH * SEQ)   // 8192

typedef _Float16 f16;
typedef __attribute__((ext_vector_type(8))) _Float16 f16x8;
typedef __attribute__((ext_vector_type(4))) _Float16 f16x4;
typedef __attribute__((ext_vector_type(2))) _Float16 f16x2;
typedef __attribute__((ext_vector_type(4))) float    fx4;

typedef __attribute__((address_space(3))) char  lds_char;
typedef __attribute__((address_space(1))) const char glb_char;

#define SCALE_Q 0.18033688011112042f   // 0.125 * log2(e), folded into Q at GEMM1

// Raw barrier + counted waits (the whole point: __syncthreads() emits
// s_waitcnt vmcnt(0) and drains the stage-ahead pipeline every tile).
#define BAR_LGKM()  asm volatile("s_waitcnt lgkmcnt(0)\n\ts_barrier" ::: "memory")
#define BAR_VM8()   asm volatile("s_waitcnt vmcnt(8)\n\ts_barrier" ::: "memory")
#define BAR_VM0()   asm volatile("s_waitcnt vmcnt(0)\n\ts_barrier" ::: "memory")

// ---------------------------------------------------------------------------
// Fused prep (unchanged).
// ---------------------------------------------------------------------------
__global__ __launch_bounds__(256) void prep(const float* __restrict__ x,
                                            f16* __restrict__ x_h,
                                            const float* __restrict__ Wqkv,
                                            f16* __restrict__ Wqt,
                                            const float* __restrict__ Wproj,
                                            f16* __restrict__ Wpt) {
    const int blk = blockIdx.x;
    if (blk < 8192) {
        const int i = (blk * 256 + threadIdx.x) * 4;
        const float4 v = *(const float4*)(x + i);
        f16x4 o = {(f16)v.x, (f16)v.y, (f16)v.z, (f16)v.w};
        *(f16x4*)(x_h + i) = o;
        return;
    }
    __shared__ float t[32][33];
    const float* W;
    f16* Wt;
    int N, bx, by;
    if (blk < 8192 + 3072) {
        const int b2 = blk - 8192;
        W = Wqkv; Wt = Wqt; N = 3072; bx = b2 % 96; by = b2 / 96;
    } else {
        const int b2 = blk - 8192 - 3072;
        W = Wproj; Wt = Wpt; N = 1024; bx = b2 % 32; by = b2 / 32;
    }
    const int tx = threadIdx.x & 31, ty = threadIdx.x >> 5;   // 32 x 8
    const int k0 = by * 32, n0 = bx * 32;
    #pragma unroll
    for (int i = 0; i < 4; i++)
        t[ty + i * 8][tx] = W[(size_t)(k0 + ty + i * 8) * N + n0 + tx];
    __syncthreads();
    #pragma unroll
    for (int i = 0; i < 4; i++)
        Wt[(size_t)(n0 + ty + i * 8) * 1024 + k0 + tx] = (f16)t[tx][ty + i * 8];
}

// ---------------------------------------------------------------------------
// f16 MFMA GEMM v4: counted-vmcnt double-buffered pipeline (T3+T4).
// Round-7 post-mortem: v3's __syncthreads() drains vmcnt(0) -> the ahead-by-2
// stage was nullified (every tile paid a full drain). v4 uses raw s_barrier
// with counted waits:
//   per iter: ds_read 16 frags (buf cur) -> lgkmcnt(0)+barrier (buf free, NO
//   vm drain) -> STAGE(buf cur, t+2) (8 loads in flight) -> 32 MFMA under
//   setprio -> vmcnt(8)+barrier (completes tile t+1's loads; t+2's 8 stay
//   in flight across the next full iteration).
// vmcnt audit: STAGE = 8 VMEM/wave; prologue 16 outstanding -> vmcnt(8) =
// tile0 done; steady loop 16 outstanding -> vmcnt(8) = t+1 done; last two
// iters (no stage) use vmcnt(0). NT = K/64 = 16, even, no tail.
// BK=64 + chunk-XOR swizzle (round-5-verified math, 0 conflicts): per m252
// the conflict fix becomes visible once the drain is amortized.
// BM=128 both modes; LDS = 4 x [128][64] f16 = 64 KB -> 2 blocks/CU.
// Epilogues verbatim from passing v3: Q/K direct, V LDS-bounce, fp32 C.
// ---------------------------------------------------------------------------
template <int MODE>
__global__ __launch_bounds__(256) void gemm_f16k(const f16* __restrict__ A,
                                                 const f16* __restrict__ Bt,
                                                 const float* __restrict__ bias,
                                                 float* __restrict__ Cf,
                                                 f16* __restrict__ qH,
                                                 f16* __restrict__ kH,
                                                 f16* __restrict__ vT,
                                                 int M, int N, int K) {
    constexpr int TEL = 128 * 64;                       // f16 per buffer
    __shared__ alignas(16) f16 smem[4 * TEL];           // 64 KB

    f16 (*As0)[64] = (f16(*)[64])(smem);
    f16 (*As1)[64] = (f16(*)[64])(smem + TEL);
    f16 (*Bs0)[64] = (f16(*)[64])(smem + 2 * TEL);
    f16 (*Bs1)[64] = (f16(*)[64])(smem + 3 * TEL);
    lds_char* a0b = (lds_char*)smem;
    lds_char* a1b = (lds_char*)smem + 2 * TEL;          // bytes
    lds_char* b0b = (lds_char*)smem + 4 * TEL;
    lds_char* b1b = (lds_char*)smem + 6 * TEL;

    const int tid  = threadIdx.x;
    const int wave = tid >> 6;
    const int lane = tid & 63;
    const int quad = lane >> 4;
    const int l16  = lane & 15;

    // XCD-aware bijective chunk swizzle (nwg % 8 == 0 at both call sites).
    const int nwg  = gridDim.x * gridDim.y;
    const int flat = blockIdx.y * gridDim.x + blockIdx.x;
    const int swz  = (flat & 7) * (nwg >> 3) + (flat >> 3);
    const int bx   = swz % gridDim.x;
    const int by   = swz / gridDim.x;
    const int m0   = by * 128;
    const int n0   = bx * 128;
    const int wm   = wave & 1;
    const int wn   = wave >> 1;

    fx4 acc[4][4];
    #pragma unroll
    for (int i = 0; i < 4; i++)
        #pragma unroll
        for (int j = 0; j < 4; j++)
            acc[i][j] = (fx4){0.f, 0.f, 0.f, 0.f};

    // Staging (round-5-verified): group g covers 8 rows (1 KB); lane's 16B
    // land at row g*8 + (lane>>3), physical chunk lane&7. Source k-chunk =
    // phys ^ (row&7) -> swizzle lives in the per-lane GLOBAL address.
    const int srow = lane >> 3;
    const int sjl  = ((lane & 7) ^ (srow & 7)) * 8;     // f16 offset
    auto STAGE = [&](lds_char* asb, lds_char* bsb, int k0) {   // 8 VMEM/wave
        #pragma unroll
        for (int it = 0; it < 4; it++) {
            const int g = it * 4 + wave;
            const int r = g * 8 + srow;
            __builtin_amdgcn_global_load_lds(
                (glb_char*)(A + (size_t)(m0 + r) * K + k0 + sjl),
                asb + g * 1024, 16, 0, 0);
            __builtin_amdgcn_global_load_lds(
                (glb_char*)(Bt + (size_t)(n0 + r) * K + k0 + sjl),
                bsb + g * 1024, 16, 0, 0);
        }
    };

    const int NT = K >> 6;   // 16

    auto ITER = [&](f16 (*As)[64], f16 (*Bs)[64],
                    lds_char* asb, lds_char* bsb, int t) {
        // ---- read ALL fragments of tile t (16 x b128, swizzled chunks) ----
        f16x8 af0[4], af1[4], bf0[4], bf1[4];
        #pragma unroll
        for (int i = 0; i < 4; i++) {
            const int ra = wm * 64 + i * 16 + l16;
            const int rb = wn * 64 + i * 16 + l16;
            af0[i] = *(const f16x8*)&As[ra][((0 + quad) ^ (ra & 7)) * 8];
            af1[i] = *(const f16x8*)&As[ra][((4 + quad) ^ (ra & 7)) * 8];
            bf0[i] = *(const f16x8*)&Bs[rb][((0 + quad) ^ (rb & 7)) * 8];
            bf1[i] = *(const f16x8*)&Bs[rb][((4 + quad) ^ (rb & 7)) * 8];
        }
        // my reads done + all waves' reads done -> buf free. NO vm drain.
        BAR_LGKM();
        const bool more = (t + 2 < NT);
        if (more) STAGE(asb, bsb, (t + 2) * 64);   // 8 loads, fly 2 iters
        __builtin_amdgcn_s_setprio(1);
        #pragma unroll
        for (int i = 0; i < 4; i++)
            #pragma unroll
            for (int j = 0; j < 4; j++) {
                acc[i][j] = __builtin_amdgcn_mfma_f32_16x16x32_f16(af0[i], bf0[j], acc[i][j], 0, 0, 0);
                acc[i][j] = __builtin_amdgcn_mfma_f32_16x16x32_f16(af1[i], bf1[j], acc[i][j], 0, 0, 0);
            }
        __builtin_amdgcn_s_setprio(0);
        // completes tile t+1's 8 loads; t+2's 8 remain in flight.
        if (more) BAR_VM8(); else BAR_VM0();
    };

    STAGE(a0b, b0b, 0);
    STAGE(a1b, b1b, 64);
    BAR_VM8();               // tile 0 complete for ALL waves; tile 1 in flight

    for (int t = 0; t < NT; t += 2) {
        ITER(As0, Bs0, a0b, b0b, t);
        ITER(As1, Bs1, a1b, b1b, t + 1);
    }

    const int region = (MODE == 1) ? (n0 >> 10) : 0;

    if (MODE == 1 && region == 2) {
        // ---- V epilogue via LDS bounce (block-uniform branch, v3-verified) --
        const int b  = m0 >> 11;
        const int s0 = m0 & 2047;
        #pragma unroll
        for (int i = 0; i < 4; i++) {
            #pragma unroll
            for (int j = 0; j < 4; j++) {
                const int nloc = wn * 64 + j * 16 + l16;
                const float bn = bias[n0 + nloc];
                #pragma unroll
                for (int r = 0; r < 4; r++) {
                    const int sloc = wm * 64 + i * 16 + quad * 4 + r;
                    const int sp   = (sloc & ~31) | ((sloc & 15) << 1) | ((sloc >> 4) & 1);
                    const int phys = (sp >> 3) ^ (nloc & 15);
                    smem[nloc * 128 + phys * 8 + (sp & 7)] = (f16)(acc[i][j][r] + bn);
                }
            }
        }
        __syncthreads();
        const int nl = tid >> 1;                 // 0..127 local n
        const int hf = tid & 1;                  // s half
        const int np0 = n0 - 2048;
        f16* dst = vT + ((size_t)(b * 16 + ((np0 + nl) >> 6)) * HD + (nl & 63)) * SEQ
                      + s0 + hf * 64;
        #pragma unroll
        for (int ch = 0; ch < 8; ch++) {
            const int lc   = hf * 8 + ch;
            const int phys = lc ^ (nl & 15);
            const f16x8 v  = *(const f16x8*)&smem[nl * 128 + phys * 8];
            *(f16x8*)(dst + ch * 8) = v;
        }
        return;
    }

    #pragma unroll
    for (int i = 0; i < 4; i++) {
        const int mb = m0 + wm * 64 + i * 16 + quad * 4;
        #pragma unroll
        for (int j = 0; j < 4; j++) {
            const int n  = n0 + wn * 64 + j * 16 + l16;
            const float bn = bias[n];
            #pragma unroll
            for (int r = 0; r < 4; r++) {
                const int m = mb + r;
                const float v = acc[i][j][r] + bn;
                if (MODE == 0) {
                    Cf[(size_t)m * N + n] = v;
                } else {
                    const int b = m >> 11, s = m & 2047;
                    if (region == 0) {
                        qH[(size_t)m * EMBED + n] = (f16)(v * SCALE_Q);
                    } else {   // region 1: K
                        const int np = n - 1024, hh = np >> 6, d = np & 63;
                        kH[(((size_t)(b * 16 + hh) * SEQ + s) << 6) + d] = (f16)v;
                    }
                }
            }
        }
    }
}

// ---------------------------------------------------------------------------
// MFMA flash attention v8 (unchanged from rounds 4-7): single-buffered K/V,
// phase-ordered async stage, raw v_exp_f32 softmax, XOR-swizzled LDS,
// ones-column row sums, XCD swizzle. Its stage->drain pairs each sit a full
// compute phase after issue, so latency is already mostly hidden. ~85us.
// ---------------------------------------------------------------------------
__global__ __launch_bounds__(256, 4) void attn_mfma(const f16* __restrict__ qH,
                                                    const f16* __restrict__ kH,
                                                    const f16* __restrict__ vT,
                                                    f16* __restrict__ ctx) {
    __shared__ alignas(16) f16 Ks[64 * 64];        // 8 KB, swizzled [key][dim]
    __shared__ alignas(16) f16 Vt[64 * 64];        // 8 KB, swizzled [dim][keycol]
    __shared__ alignas(16) f16 Pl[4][2][16 * 64];  // 16 KB, chunk-xor swizzled

    const int tid  = threadIdx.x;
    const int wave = tid >> 6;
    const int lane = tid & 63;
    const int quad = lane >> 4;
    const int l16  = lane & 15;

    const int bid = (int)blockIdx.x;
    const int swz = (bid & 7) * 128 + (bid >> 3);
    const int qb = swz & 15;
    const int bh = swz >> 4;
    const int h  = bh & 15;
    const int b  = bh >> 4;
    const int q0 = qb * 128 + wave * 32;

    const f16* kB = kH + (size_t)bh * SEQ * HD;
    const f16* vB = vT + (size_t)bh * HD * SEQ;

    f16x8 qf[2][2];
    #pragma unroll
    for (int s = 0; s < 2; s++) {
        const f16* qp = qH + (size_t)(b * SEQ + q0 + s * 16 + l16) * EMBED + h * HD;
        #pragma unroll
        for (int c = 0; c < 2; c++)
            qf[s][c] = *(const f16x8*)(qp + c * 32 + quad * 8);
    }

    fx4 o[2][4];
    fx4 ls[2];
    #pragma unroll
    for (int s = 0; s < 2; s++) {
        ls[s] = (fx4){0.f, 0.f, 0.f, 0.f};
        #pragma unroll
        for (int dc = 0; dc < 4; dc++)
            o[s][dc] = (fx4){0.f, 0.f, 0.f, 0.f};
    }

    f16x8 ones8;
    #pragma unroll
    for (int j = 0; j < 8; j++) ones8[j] = (f16)1.0f;

    lds_char* ksb = (lds_char*)&Ks[0];
    lds_char* vsb = (lds_char*)&Vt[0];

    auto STAGE_K = [&](int kb) {
        #pragma unroll
        for (int it = 0; it < 2; it++) {
            const int g  = wave * 2 + it;
            const int c  = g * 64 + lane;
            const int r  = c >> 3;
            const int jl = (c & 7) ^ (r & 7);
            __builtin_amdgcn_global_load_lds(
                (glb_char*)(kB + (size_t)(kb * 64 + r) * HD + jl * 8),
                ksb + g * 1024, 16, 0, 0);
        }
    };
    auto STAGE_V = [&](int kb) {
        #pragma unroll
        for (int it = 0; it < 2; it++) {
            const int g  = wave * 2 + it;
            const int c  = g * 64 + lane;
            const int r  = c >> 3;
            const int jl = (c & 7) ^ (r & 7);
            __builtin_amdgcn_global_load_lds(
                (glb_char*)(vB + (size_t)r * SEQ + kb * 64 + jl * 8),
                vsb + g * 1024, 16, 0, 0);
        }
    };

    STAGE_K(0);
    STAGE_V(0);
    __syncthreads();

    for (int kb = 0; kb < SEQ / 64; kb++) {
        fx4 st0[4], st1[4];
        __builtin_amdgcn_s_setprio(1);
        #pragma unroll
        for (int t = 0; t < 4; t++) {
            const int row = l16 + 16 * t;
            const f16x8 kt0 = *(const f16x8*)&Ks[(row * 8 + ((0 + quad) ^ (row & 7))) * 8];
            const f16x8 kt1 = *(const f16x8*)&Ks[(row * 8 + ((4 + quad) ^ (row & 7))) * 8];
            fx4 z = {0.f, 0.f, 0.f, 0.f};
            st0[t] = __builtin_amdgcn_mfma_f32_16x16x32_f16(qf[0][0], kt0, z, 0, 0, 0);
            st0[t] = __builtin_amdgcn_mfma_f32_16x16x32_f16(qf[0][1], kt1, st0[t], 0, 0, 0);
            st1[t] = __builtin_amdgcn_mfma_f32_16x16x32_f16(qf[1][0], kt0, z, 0, 0, 0);
            st1[t] = __builtin_amdgcn_mfma_f32_16x16x32_f16(qf[1][1], kt1, st1[t], 0, 0, 0);
        }
        __builtin_amdgcn_s_setprio(0);

        #pragma unroll
        for (int g = 0; g < 2; g++)
            #pragma unroll
            for (int r = 0; r < 4; r++) {
                const int row = quad * 4 + r;
                const int cc  = (g * 4 + (l16 >> 2)) ^ (row & 7);
                {
                    const float pa = __builtin_amdgcn_exp2f(st0[2 * g][r]);
                    const float pb = __builtin_amdgcn_exp2f(st0[2 * g + 1][r]);
                    const f16x2 pk = __builtin_bit_cast(f16x2, __builtin_amdgcn_cvt_pkrtz(pa, pb));
                    *(f16x2*)&Pl[wave][0][row * 64 + cc * 8 + (l16 & 3) * 2] = pk;
                }
                {
                    const float pa = __builtin_amdgcn_exp2f(st1[2 * g][r]);
                    const float pb = __builtin_amdgcn_exp2f(st1[2 * g + 1][r]);
                    const f16x2 pk = __builtin_bit_cast(f16x2, __builtin_amdgcn_cvt_pkrtz(pa, pb));
                    *(f16x2*)&Pl[wave][1][row * 64 + cc * 8 + (l16 & 3) * 2] = pk;
                }
            }

        __syncthreads();
        if (kb + 1 < SEQ / 64) STAGE_K(kb + 1);

        const f16x8 pf00 = *(const f16x8*)&Pl[wave][0][l16 * 64 + ((0 + quad) ^ (l16 & 7)) * 8];
        const f16x8 pf01 = *(const f16x8*)&Pl[wave][0][l16 * 64 + ((4 + quad) ^ (l16 & 7)) * 8];
        const f16x8 pf10 = *(const f16x8*)&Pl[wave][1][l16 * 64 + ((0 + quad) ^ (l16 & 7)) * 8];
        const f16x8 pf11 = *(const f16x8*)&Pl[wave][1][l16 * 64 + ((4 + quad) ^ (l16 & 7)) * 8];
        __builtin_amdgcn_s_setprio(1);
        #pragma unroll
        for (int dc = 0; dc < 4; dc++) {
            const int row = 16 * dc + l16;
            const f16x8 vf0 = *(const f16x8*)&Vt[(row * 8 + ((0 + quad) ^ (row & 7))) * 8];
            const f16x8 vf1 = *(const f16x8*)&Vt[(row * 8 + ((4 + quad) ^ (row & 7))) * 8];
            o[0][dc] = __builtin_amdgcn_mfma_f32_16x16x32_f16(pf00, vf0, o[0][dc], 0, 0, 0);
            o[0][dc] = __builtin_amdgcn_mfma_f32_16x16x32_f16(pf01, vf1, o[0][dc], 0, 0, 0);
            o[1][dc] = __builtin_amdgcn_mfma_f32_16x16x32_f16(pf10, vf0, o[1][dc], 0, 0, 0);
            o[1][dc] = __builtin_amdgcn_mfma_f32_16x16x32_f16(pf11, vf1, o[1][dc], 0, 0, 0);
        }
        ls[0] = __builtin_amdgcn_mfma_f32_16x16x32_f16(pf00, ones8, ls[0], 0, 0, 0);
        ls[0] = __builtin_amdgcn_mfma_f32_16x16x32_f16(pf01, ones8, ls[0], 0, 0, 0);
        ls[1] = __builtin_amdgcn_mfma_f32_16x16x32_f16(pf10, ones8, ls[1], 0, 0, 0);
        ls[1] = __builtin_amdgcn_mfma_f32_16x16x32_f16(pf11, ones8, ls[1], 0, 0, 0);
        __builtin_amdgcn_s_setprio(0);

        __syncthreads();
        if (kb + 1 < SEQ / 64) STAGE_V(kb + 1);
    }

    #pragma unroll
    for (int s = 0; s < 2; s++) {
        #pragma unroll
        for (int r = 0; r < 4; r++) {
            const float inv = 1.0f / ls[s][r];
            const int q = q0 + s * 16 + quad * 4 + r;
            f16* dst = ctx + (size_t)(b * SEQ + q) * EMBED + h * HD;
            #pragma unroll
            for (int dc = 0; dc < 4; dc++)
                dst[dc * 16 + l16] = (f16)(o[s][dc][r] * inv);
        }
    }
}

// ---------------------------------------------------------------------------
extern "C" void kernel_launch(void* const* d_in, const int* in_sizes, int n_in,
                              void* d_out, int out_size, void* d_ws, size_t ws_size,
                              hipStream_t stream) {
    const float* x     = (const float*)d_in[0];
    const float* Wqkv  = (const float*)d_in[1];
    const float* bqkv  = (const float*)d_in[2];
    const float* Wproj = (const float*)d_in[3];
    const float* bproj = (const float*)d_in[4];
    float* out = (float*)d_out;

    f16* x_h = (f16*)d_ws;                          // 8M
    f16* qHb = x_h + (size_t)ROWS * EMBED;          // 8M
    f16* kHb = qHb + (size_t)ROWS * EMBED;          // 8M
    f16* vTb = kHb + (size_t)ROWS * EMBED;          // 8M
    f16* ctx = vTb + (size_t)ROWS * EMBED;          // 8M
    f16* Wqt = ctx + (size_t)ROWS * EMBED;          // 3M
    f16* Wpt = Wqt + (size_t)3 * EMBED * EMBED;     // 1M

    // 0) fused conversions (x, Wqkv^T, Wproj^T)
    prep<<<dim3(12288), dim3(256), 0, stream>>>(x, x_h, Wqkv, Wqt, Wproj, Wpt);

    // 1) qkv GEMM (BM=128): grid (24, 64) = 1536 blocks
    gemm_f16k<1><<<dim3(3 * EMBED / 128, ROWS / 128), dim3(256), 0, stream>>>(
        x_h, Wqt, bqkv, nullptr, qHb, kHb, vTb, ROWS, 3 * EMBED, EMBED);

    // 2) flash attention
    attn_mfma<<<dim3(64 * 16), dim3(256), 0, stream>>>(qHb, kHb, vTb, ctx);

    // 3) out = ctx @ Wproj + bias (BM=128): grid (8, 64) = 512 blocks
    gemm_f16k<0><<<dim3(EMBED / 128, ROWS / 128), dim3(256), 0, stream>>>(
        ctx, Wpt, bproj, out, nullptr, nullptr, nullptr, ROWS, EMBED, EMBED);
}